// Round 1
// baseline (2533.369 us; speedup 1.0000x reference)
//
#include <hip/hip_runtime.h>
#include <hip/hip_bf16.h>

// GraphSAGE 2-layer, N=100000 nodes, E=640000 edges, d=128 -> 128 -> 64.
// Layer: out = (agg/deg) @ Wl + b + x @ Wr ; layer1 + relu.
//
// Round 1 strategy: correctness-first baseline.
//   - scatter: 32 lanes/edge, float4 gather of x[src], fp32 HW atomics into agg[dst]
//   - sage: fused fp32 GEMM [NT,256]@[256,NC] with LDS A-tile + W chunks, 4x4 reg blocking

#define NNODES 100000
#define NEDGES 640000

__global__ void scatter_kernel(const float* __restrict__ feat,
                               const int* __restrict__ src,
                               const int* __restrict__ dst,
                               float* __restrict__ agg,
                               float* __restrict__ deg,
                               int E, int do_deg)
{
    int gid = blockIdx.x * blockDim.x + threadIdx.x;
    int e = gid >> 5;
    int lane = gid & 31;
    if (e >= E) return;
    int s = src[e];
    int d = dst[e];
    float4 v = reinterpret_cast<const float4*>(feat + (size_t)s * 128)[lane];
    float* outp = agg + (size_t)d * 128 + lane * 4;
    unsafeAtomicAdd(outp + 0, v.x);
    unsafeAtomicAdd(outp + 1, v.y);
    unsafeAtomicAdd(outp + 2, v.z);
    unsafeAtomicAdd(outp + 3, v.w);
    if (do_deg && lane == 0) unsafeAtomicAdd(deg + d, 1.0f);
}

// out[node][c] = sum_k ( [mean | feat][node][k] * [Wl ; Wr][k][c] ) + bias[c]
// K = 256 (128 mean + 128 self). NC = 128 (layer1, relu) or 64 (layer2).
template<int NC, bool RELU>
__global__ __launch_bounds__(256)
void sage_kernel(const float* __restrict__ feat,   // [N,128] self features
                 const float* __restrict__ agg,    // [N,128] summed messages
                 const float* __restrict__ deg,    // [N]
                 const float* __restrict__ Wl,     // [128,NC]
                 const float* __restrict__ Wr,     // [128,NC]
                 const float* __restrict__ bias,   // [NC]
                 float* __restrict__ out,          // [N,NC]
                 int N)
{
    constexpr int CG = NC / 4;       // col groups (threads along cols)
    constexpr int NG = 256 / CG;     // node groups
    constexpr int NT = NG * 4;       // nodes per block (32 for NC=128, 64 for NC=64)

    __shared__ float A[NT][256];
    __shared__ float Wt[32][NC];

    const int base = blockIdx.x * NT;

    // ---- stage A tile: [mean | self] per node, float4 loads ----
    for (int i = threadIdx.x; i < NT * 64; i += 256) {   // i indexes float4s
        int n = i >> 6;           // 64 float4s per 256-float row
        int k4 = i & 63;
        int node = base + n;
        float4 v = make_float4(0.f, 0.f, 0.f, 0.f);
        if (node < N) {
            if (k4 < 32) {
                v = reinterpret_cast<const float4*>(agg + (size_t)node * 128)[k4];
                float dg = deg[node];
                dg = dg > 1.f ? dg : 1.f;
                float inv = 1.f / dg;
                v.x *= inv; v.y *= inv; v.z *= inv; v.w *= inv;
            } else {
                v = reinterpret_cast<const float4*>(feat + (size_t)node * 128)[k4 - 32];
            }
        }
        *reinterpret_cast<float4*>(&A[n][k4 * 4]) = v;
    }

    const int cg = threadIdx.x % CG;
    const int ng = threadIdx.x / CG;
    const int c0 = cg * 4;
    const int r0 = ng * 4;

    float acc[4][4];
    #pragma unroll
    for (int r = 0; r < 4; ++r)
        #pragma unroll
        for (int c = 0; c < 4; ++c) acc[r][c] = 0.f;

    for (int kc = 0; kc < 8; ++kc) {
        __syncthreads();
        // stage W chunk: combined rows [kc*32, kc*32+32); rows 0-127 = Wl, 128-255 = Wr
        for (int i = threadIdx.x; i < 32 * CG; i += 256) {
            int r = i / CG;
            int c4 = i % CG;
            int gk = kc * 32 + r;
            const float* wsrc = (gk < 128) ? (Wl + (size_t)gk * NC + c4 * 4)
                                           : (Wr + (size_t)(gk - 128) * NC + c4 * 4);
            *reinterpret_cast<float4*>(&Wt[r][c4 * 4]) = *reinterpret_cast<const float4*>(wsrc);
        }
        __syncthreads();

        const int kb = kc * 32;
        #pragma unroll
        for (int k4 = 0; k4 < 8; ++k4) {
            float4 a0 = *reinterpret_cast<const float4*>(&A[r0 + 0][kb + k4 * 4]);
            float4 a1 = *reinterpret_cast<const float4*>(&A[r0 + 1][kb + k4 * 4]);
            float4 a2 = *reinterpret_cast<const float4*>(&A[r0 + 2][kb + k4 * 4]);
            float4 a3 = *reinterpret_cast<const float4*>(&A[r0 + 3][kb + k4 * 4]);
            float4 b0 = *reinterpret_cast<const float4*>(&Wt[k4 * 4 + 0][c0]);
            float4 b1 = *reinterpret_cast<const float4*>(&Wt[k4 * 4 + 1][c0]);
            float4 b2 = *reinterpret_cast<const float4*>(&Wt[k4 * 4 + 2][c0]);
            float4 b3 = *reinterpret_cast<const float4*>(&Wt[k4 * 4 + 3][c0]);
            #define ACCUM(r, av)                                                      \
                acc[r][0] += av.x * b0.x; acc[r][1] += av.x * b0.y;                   \
                acc[r][2] += av.x * b0.z; acc[r][3] += av.x * b0.w;                   \
                acc[r][0] += av.y * b1.x; acc[r][1] += av.y * b1.y;                   \
                acc[r][2] += av.y * b1.z; acc[r][3] += av.y * b1.w;                   \
                acc[r][0] += av.z * b2.x; acc[r][1] += av.z * b2.y;                   \
                acc[r][2] += av.z * b2.z; acc[r][3] += av.z * b2.w;                   \
                acc[r][0] += av.w * b3.x; acc[r][1] += av.w * b3.y;                   \
                acc[r][2] += av.w * b3.z; acc[r][3] += av.w * b3.w;
            ACCUM(0, a0)
            ACCUM(1, a1)
            ACCUM(2, a2)
            ACCUM(3, a3)
            #undef ACCUM
        }
    }

    // ---- epilogue: bias (+relu), float4 store ----
    #pragma unroll
    for (int r = 0; r < 4; ++r) {
        int node = base + r0 + r;
        if (node >= N) continue;
        float4 o;
        o.x = acc[r][0] + bias[c0 + 0];
        o.y = acc[r][1] + bias[c0 + 1];
        o.z = acc[r][2] + bias[c0 + 2];
        o.w = acc[r][3] + bias[c0 + 3];
        if (RELU) {
            o.x = fmaxf(o.x, 0.f); o.y = fmaxf(o.y, 0.f);
            o.z = fmaxf(o.z, 0.f); o.w = fmaxf(o.w, 0.f);
        }
        *reinterpret_cast<float4*>(out + (size_t)node * NC + c0) = o;
    }
}

extern "C" void kernel_launch(void* const* d_in, const int* in_sizes, int n_in,
                              void* d_out, int out_size, void* d_ws, size_t ws_size,
                              hipStream_t stream)
{
    const float* x   = (const float*)d_in[0];
    const int*   ei  = (const int*)d_in[1];   // [2,E] int32 (jax default int)
    const float* W1l = (const float*)d_in[2];
    const float* b1  = (const float*)d_in[3];
    const float* W1r = (const float*)d_in[4];
    const float* W2l = (const float*)d_in[5];
    const float* b2  = (const float*)d_in[6];
    const float* W2r = (const float*)d_in[7];
    float* out = (float*)d_out;

    const int N = NNODES, E = NEDGES;
    const int* src = ei;
    const int* dst = ei + E;

    char* ws = (char*)d_ws;
    const size_t deg_pad = 4096 * (((size_t)N * 4 + 4095) / 4096);  // 401408 B
    const size_t agg_bytes = (size_t)N * 128 * 4;                    // 51.2 MB
    float* deg = (float*)ws;
    float* agg = (float*)(ws + deg_pad);
    float* h   = (float*)(ws + deg_pad + agg_bytes);

    // zero deg + agg
    hipMemsetAsync(ws, 0, deg_pad + agg_bytes, stream);

    const int sgrid = (E * 32) / 256;   // 80000 blocks, exact

    // ---- layer 1 ----
    scatter_kernel<<<sgrid, 256, 0, stream>>>(x, src, dst, agg, deg, E, 1);
    sage_kernel<128, true><<<(N + 31) / 32, 256, 0, stream>>>(x, agg, deg, W1l, W1r, b1, h, N);

    // re-zero agg for layer 2
    hipMemsetAsync(agg, 0, agg_bytes, stream);

    // ---- layer 2 ----
    scatter_kernel<<<sgrid, 256, 0, stream>>>(h, src, dst, agg, deg, E, 0);
    sage_kernel<64, false><<<(N + 63) / 64, 256, 0, stream>>>(h, agg, deg, W2l, W2r, b2, out, N);
}

// Round 3
// 415.011 us; speedup vs baseline: 6.1043x; 6.1043x over previous
//
#include <hip/hip_runtime.h>
#include <hip/hip_bf16.h>

// GraphSAGE 2-layer, N=100000, E=640000, d=128 -> 128 -> 64.
// Round 2 (resubmit; broker timeout): replace fp32-atomic scatter (2x1108us,
// atomic-bound) with CSR build (hist + scan + bucket) + atomic-free gather-mean.
// Layer 2 uses transform-first: gather h@W2l (64 dims) instead of h (128 dims).

#define NNODES 100000
#define NEDGES 640000

// ---------------- CSR build ----------------

__global__ void hist_kernel(const int* __restrict__ dst, int* __restrict__ count, int E) {
    int e = blockIdx.x * blockDim.x + threadIdx.x;
    if (e < E) atomicAdd(&count[dst[e]], 1);
}

__global__ void block_sum_kernel(const int* __restrict__ count, int* __restrict__ bsum, int N) {
    __shared__ int s[256];
    int t = threadIdx.x;
    int i = blockIdx.x * 256 + t;
    s[t] = (i < N) ? count[i] : 0;
    __syncthreads();
    for (int off = 128; off > 0; off >>= 1) {
        if (t < off) s[t] += s[t + off];
        __syncthreads();
    }
    if (t == 0) bsum[blockIdx.x] = s[0];
}

__global__ void scan_bsum_kernel(int* __restrict__ bsum, int nb) {
    __shared__ int s[512];
    int t = threadIdx.x;
    int orig = (t < nb) ? bsum[t] : 0;
    s[t] = orig;
    __syncthreads();
    for (int off = 1; off < 512; off <<= 1) {
        int v = (t >= off) ? s[t - off] : 0;
        __syncthreads();
        s[t] += v;
        __syncthreads();
    }
    if (t < nb) bsum[t] = s[t] - orig;   // exclusive
}

__global__ void scan_write_kernel(const int* __restrict__ count, const int* __restrict__ bsum,
                                  int* __restrict__ rp, int N, int E) {
    __shared__ int s[256];
    int t = threadIdx.x;
    int i = blockIdx.x * 256 + t;
    int orig = (i < N) ? count[i] : 0;
    s[t] = orig;
    __syncthreads();
    for (int off = 1; off < 256; off <<= 1) {
        int v = (t >= off) ? s[t - off] : 0;
        __syncthreads();
        s[t] += v;
        __syncthreads();
    }
    if (i < N) rp[i] = bsum[blockIdx.x] + s[t] - orig;   // exclusive global
    if (i == 0) rp[N] = E;
}

__global__ void bucket_kernel(const int* __restrict__ src, const int* __restrict__ dst,
                              const int* __restrict__ rp, int* __restrict__ cursor,
                              int* __restrict__ esrc, int E) {
    int e = blockIdx.x * blockDim.x + threadIdx.x;
    if (e >= E) return;
    int d = dst[e];
    int pos = atomicAdd(&cursor[d], 1);
    esrc[rp[d] + pos] = src[e];
}

// ---------------- gathers (atomic-free) ----------------

// mean[n][0:128] = (1/max(deg,1)) * sum_{j in N(n)} feat[j][0:128]
__global__ __launch_bounds__(256)
void gather_mean128_kernel(const float* __restrict__ feat, const int* __restrict__ rp,
                           const int* __restrict__ esrc, float* __restrict__ mean, int N) {
    int gid = blockIdx.x * 256 + threadIdx.x;
    int n = gid >> 5, lane = gid & 31;
    if (n >= N) return;
    int beg = rp[n], end = rp[n + 1];
    float4 acc = make_float4(0.f, 0.f, 0.f, 0.f);
    int j = beg;
    for (; j + 2 <= end; j += 2) {
        int s0 = esrc[j], s1 = esrc[j + 1];
        float4 v0 = reinterpret_cast<const float4*>(feat + (size_t)s0 * 128)[lane];
        float4 v1 = reinterpret_cast<const float4*>(feat + (size_t)s1 * 128)[lane];
        acc.x += v0.x + v1.x; acc.y += v0.y + v1.y;
        acc.z += v0.z + v1.z; acc.w += v0.w + v1.w;
    }
    if (j < end) {
        int s0 = esrc[j];
        float4 v0 = reinterpret_cast<const float4*>(feat + (size_t)s0 * 128)[lane];
        acc.x += v0.x; acc.y += v0.y; acc.z += v0.z; acc.w += v0.w;
    }
    float inv = 1.0f / fmaxf((float)(end - beg), 1.0f);
    float4 o = make_float4(acc.x * inv, acc.y * inv, acc.z * inv, acc.w * inv);
    reinterpret_cast<float4*>(mean + (size_t)n * 128)[lane] = o;
}

// out[n][0:64] = (1/max(deg,1)) * sum_j q[src_j][0:64]  +  q[n][64:128]
__global__ __launch_bounds__(256)
void gather_out64_kernel(const float* __restrict__ q, const int* __restrict__ rp,
                         const int* __restrict__ esrc, float* __restrict__ out, int N) {
    int gid = blockIdx.x * 256 + threadIdx.x;
    int n = gid >> 4, lane = gid & 15;
    if (n >= N) return;
    int beg = rp[n], end = rp[n + 1];
    float4 acc = make_float4(0.f, 0.f, 0.f, 0.f);
    int j = beg;
    for (; j + 2 <= end; j += 2) {
        int s0 = esrc[j], s1 = esrc[j + 1];
        float4 v0 = reinterpret_cast<const float4*>(q + (size_t)s0 * 128)[lane];
        float4 v1 = reinterpret_cast<const float4*>(q + (size_t)s1 * 128)[lane];
        acc.x += v0.x + v1.x; acc.y += v0.y + v1.y;
        acc.z += v0.z + v1.z; acc.w += v0.w + v1.w;
    }
    if (j < end) {
        int s0 = esrc[j];
        float4 v0 = reinterpret_cast<const float4*>(q + (size_t)s0 * 128)[lane];
        acc.x += v0.x; acc.y += v0.y; acc.z += v0.z; acc.w += v0.w;
    }
    float inv = 1.0f / fmaxf((float)(end - beg), 1.0f);
    float4 self = reinterpret_cast<const float4*>(q + (size_t)n * 128 + 64)[lane];
    float4 o = make_float4(acc.x * inv + self.x, acc.y * inv + self.y,
                           acc.z * inv + self.z, acc.w * inv + self.w);
    reinterpret_cast<float4*>(out + (size_t)n * 64)[lane] = o;
}

// ---------------- layer-1 fused GEMM: h = relu([mean|x] @ [W1l;W1r] + b1) ----------------

__global__ __launch_bounds__(256)
void sage1_kernel(const float* __restrict__ feat,   // [N,128] self
                  const float* __restrict__ mean,   // [N,128] normalized mean
                  const float* __restrict__ Wl,     // [128,128]
                  const float* __restrict__ Wr,     // [128,128]
                  const float* __restrict__ bias,   // [128]
                  float* __restrict__ out,          // [N,128]
                  int N)
{
    constexpr int NC = 128;
    constexpr int NT = 32;
    __shared__ float A[NT][256];
    __shared__ float Wt[32][NC];

    const int base = blockIdx.x * NT;

    for (int i = threadIdx.x; i < NT * 64; i += 256) {
        int n = i >> 6;
        int k4 = i & 63;
        int node = base + n;
        float4 v = make_float4(0.f, 0.f, 0.f, 0.f);
        if (node < N) {
            v = (k4 < 32)
                ? reinterpret_cast<const float4*>(mean + (size_t)node * 128)[k4]
                : reinterpret_cast<const float4*>(feat + (size_t)node * 128)[k4 - 32];
        }
        *reinterpret_cast<float4*>(&A[n][k4 * 4]) = v;
    }

    const int cg = threadIdx.x % 32;
    const int ng = threadIdx.x / 32;
    const int c0 = cg * 4;
    const int r0 = ng * 4;

    float acc[4][4];
    #pragma unroll
    for (int r = 0; r < 4; ++r)
        #pragma unroll
        for (int c = 0; c < 4; ++c) acc[r][c] = 0.f;

    for (int kc = 0; kc < 8; ++kc) {
        __syncthreads();
        for (int i = threadIdx.x; i < 32 * 32; i += 256) {
            int r = i >> 5;
            int c4 = i & 31;
            int gk = kc * 32 + r;
            const float* wsrc = (gk < 128) ? (Wl + (size_t)gk * NC + c4 * 4)
                                           : (Wr + (size_t)(gk - 128) * NC + c4 * 4);
            *reinterpret_cast<float4*>(&Wt[r][c4 * 4]) = *reinterpret_cast<const float4*>(wsrc);
        }
        __syncthreads();

        const int kb = kc * 32;
        #pragma unroll
        for (int k4 = 0; k4 < 8; ++k4) {
            float4 a0 = *reinterpret_cast<const float4*>(&A[r0 + 0][kb + k4 * 4]);
            float4 a1 = *reinterpret_cast<const float4*>(&A[r0 + 1][kb + k4 * 4]);
            float4 a2 = *reinterpret_cast<const float4*>(&A[r0 + 2][kb + k4 * 4]);
            float4 a3 = *reinterpret_cast<const float4*>(&A[r0 + 3][kb + k4 * 4]);
            float4 b0 = *reinterpret_cast<const float4*>(&Wt[k4 * 4 + 0][c0]);
            float4 b1 = *reinterpret_cast<const float4*>(&Wt[k4 * 4 + 1][c0]);
            float4 b2 = *reinterpret_cast<const float4*>(&Wt[k4 * 4 + 2][c0]);
            float4 b3 = *reinterpret_cast<const float4*>(&Wt[k4 * 4 + 3][c0]);
            #define ACCUM(r, av)                                                      \
                acc[r][0] += av.x * b0.x; acc[r][1] += av.x * b0.y;                   \
                acc[r][2] += av.x * b0.z; acc[r][3] += av.x * b0.w;                   \
                acc[r][0] += av.y * b1.x; acc[r][1] += av.y * b1.y;                   \
                acc[r][2] += av.y * b1.z; acc[r][3] += av.y * b1.w;                   \
                acc[r][0] += av.z * b2.x; acc[r][1] += av.z * b2.y;                   \
                acc[r][2] += av.z * b2.z; acc[r][3] += av.z * b2.w;                   \
                acc[r][0] += av.w * b3.x; acc[r][1] += av.w * b3.y;                   \
                acc[r][2] += av.w * b3.z; acc[r][3] += av.w * b3.w;
            ACCUM(0, a0)
            ACCUM(1, a1)
            ACCUM(2, a2)
            ACCUM(3, a3)
            #undef ACCUM
        }
    }

    #pragma unroll
    for (int r = 0; r < 4; ++r) {
        int node = base + r0 + r;
        if (node >= N) continue;
        float4 o;
        o.x = fmaxf(acc[r][0] + bias[c0 + 0], 0.f);
        o.y = fmaxf(acc[r][1] + bias[c0 + 1], 0.f);
        o.z = fmaxf(acc[r][2] + bias[c0 + 2], 0.f);
        o.w = fmaxf(acc[r][3] + bias[c0 + 3], 0.f);
        *reinterpret_cast<float4*>(out + (size_t)node * 128 + c0) = o;
    }
}

// ---------------- layer-2 transform GEMM: q = h @ [W2l | W2r], cols 64:128 get +b2 ----------------

__global__ __launch_bounds__(256)
void transform2_kernel(const float* __restrict__ h,    // [N,128]
                       const float* __restrict__ Wl,   // [128,64]
                       const float* __restrict__ Wr,   // [128,64]
                       const float* __restrict__ bias, // [64]
                       float* __restrict__ q,          // [N,128]
                       int N)
{
    constexpr int NT = 32;
    __shared__ float A[NT][128];
    __shared__ float Wt[32][128];

    const int base = blockIdx.x * NT;

    for (int i = threadIdx.x; i < NT * 32; i += 256) {
        int n = i >> 5;
        int k4 = i & 31;
        int node = base + n;
        float4 v = make_float4(0.f, 0.f, 0.f, 0.f);
        if (node < N)
            v = reinterpret_cast<const float4*>(h + (size_t)node * 128)[k4];
        *reinterpret_cast<float4*>(&A[n][k4 * 4]) = v;
    }

    const int cg = threadIdx.x % 32;
    const int ng = threadIdx.x / 32;
    const int c0 = cg * 4;
    const int r0 = ng * 4;

    float acc[4][4];
    #pragma unroll
    for (int r = 0; r < 4; ++r)
        #pragma unroll
        for (int c = 0; c < 4; ++c) acc[r][c] = 0.f;

    for (int kc = 0; kc < 4; ++kc) {
        __syncthreads();
        for (int i = threadIdx.x; i < 32 * 32; i += 256) {
            int r = i >> 5;
            int c4 = i & 31;
            int gk = kc * 32 + r;
            const float* wsrc = (c4 < 16) ? (Wl + (size_t)gk * 64 + c4 * 4)
                                          : (Wr + (size_t)gk * 64 + (c4 - 16) * 4);
            *reinterpret_cast<float4*>(&Wt[r][c4 * 4]) = *reinterpret_cast<const float4*>(wsrc);
        }
        __syncthreads();

        const int kb = kc * 32;
        #pragma unroll
        for (int k4 = 0; k4 < 8; ++k4) {
            float4 a0 = *reinterpret_cast<const float4*>(&A[r0 + 0][kb + k4 * 4]);
            float4 a1 = *reinterpret_cast<const float4*>(&A[r0 + 1][kb + k4 * 4]);
            float4 a2 = *reinterpret_cast<const float4*>(&A[r0 + 2][kb + k4 * 4]);
            float4 a3 = *reinterpret_cast<const float4*>(&A[r0 + 3][kb + k4 * 4]);
            float4 b0 = *reinterpret_cast<const float4*>(&Wt[k4 * 4 + 0][c0]);
            float4 b1 = *reinterpret_cast<const float4*>(&Wt[k4 * 4 + 1][c0]);
            float4 b2 = *reinterpret_cast<const float4*>(&Wt[k4 * 4 + 2][c0]);
            float4 b3 = *reinterpret_cast<const float4*>(&Wt[k4 * 4 + 3][c0]);
            #define ACCUM(r, av)                                                      \
                acc[r][0] += av.x * b0.x; acc[r][1] += av.x * b0.y;                   \
                acc[r][2] += av.x * b0.z; acc[r][3] += av.x * b0.w;                   \
                acc[r][0] += av.y * b1.x; acc[r][1] += av.y * b1.y;                   \
                acc[r][2] += av.y * b1.z; acc[r][3] += av.y * b1.w;                   \
                acc[r][0] += av.z * b2.x; acc[r][1] += av.z * b2.y;                   \
                acc[r][2] += av.z * b2.z; acc[r][3] += av.z * b2.w;                   \
                acc[r][0] += av.w * b3.x; acc[r][1] += av.w * b3.y;                   \
                acc[r][2] += av.w * b3.z; acc[r][3] += av.w * b3.w;
            ACCUM(0, a0)
            ACCUM(1, a1)
            ACCUM(2, a2)
            ACCUM(3, a3)
            #undef ACCUM
        }
    }

    // bias only on the self (W2r) half: cols 64..127
    float4 bv = make_float4(0.f, 0.f, 0.f, 0.f);
    if (c0 >= 64) bv = *reinterpret_cast<const float4*>(bias + (c0 - 64));

    #pragma unroll
    for (int r = 0; r < 4; ++r) {
        int node = base + r0 + r;
        if (node >= N) continue;
        float4 o;
        o.x = acc[r][0] + bv.x;
        o.y = acc[r][1] + bv.y;
        o.z = acc[r][2] + bv.z;
        o.w = acc[r][3] + bv.w;
        *reinterpret_cast<float4*>(q + (size_t)node * 128 + c0) = o;
    }
}

// ---------------- launch ----------------

extern "C" void kernel_launch(void* const* d_in, const int* in_sizes, int n_in,
                              void* d_out, int out_size, void* d_ws, size_t ws_size,
                              hipStream_t stream)
{
    const float* x   = (const float*)d_in[0];
    const int*   ei  = (const int*)d_in[1];
    const float* W1l = (const float*)d_in[2];
    const float* b1  = (const float*)d_in[3];
    const float* W1r = (const float*)d_in[4];
    const float* W2l = (const float*)d_in[5];
    const float* b2  = (const float*)d_in[6];
    const float* W2r = (const float*)d_in[7];
    float* out = (float*)d_out;

    const int N = NNODES, E = NEDGES;
    const int* src = ei;
    const int* dst = ei + E;

    char* ws = (char*)d_ws;
    int* count  = (int*)ws;                        // N
    int* cursor = count + N;                       // N
    int* rp     = cursor + N;                      // N+1
    int* bsum   = rp + N + 1;                      // 512
    int* esrc   = bsum + 512;                      // E
    float* mean = (float*)(ws + 4u * 1024u * 1024u);         // N*128 (also q2 alias)
    float* h    = (float*)(ws + 4u * 1024u * 1024u + (size_t)N * 128 * 4);

    const int nb = (N + 255) / 256;   // 391 scan blocks

    // zero count + cursor
    hipMemsetAsync(ws, 0, (size_t)2 * N * 4, stream);

    // CSR build
    hist_kernel<<<(E + 255) / 256, 256, 0, stream>>>(dst, count, E);
    block_sum_kernel<<<nb, 256, 0, stream>>>(count, bsum, N);
    scan_bsum_kernel<<<1, 512, 0, stream>>>(bsum, nb);
    scan_write_kernel<<<nb, 256, 0, stream>>>(count, bsum, rp, N, E);
    bucket_kernel<<<(E + 255) / 256, 256, 0, stream>>>(src, dst, rp, cursor, esrc, E);

    // layer 1: gather-mean(x) then fused GEMM + relu
    gather_mean128_kernel<<<(N * 32 + 255) / 256, 256, 0, stream>>>(x, rp, esrc, mean, N);
    sage1_kernel<<<(N + 31) / 32, 256, 0, stream>>>(x, mean, W1l, W1r, b1, h, N);

    // layer 2: transform-first then gather+add (q aliases mean, consumed already)
    transform2_kernel<<<(N + 31) / 32, 256, 0, stream>>>(h, W2l, W2r, b2, mean, N);
    gather_out64_kernel<<<(N * 16 + 255) / 256, 256, 0, stream>>>(mean, rp, esrc, out, N);
}

// Round 4
// 269.437 us; speedup vs baseline: 9.4025x; 1.5403x over previous
//
#include <hip/hip_runtime.h>
#include <hip/hip_bf16.h>

// GraphSAGE 2-layer, N=100000, E=640000, d=128 -> 128 -> 64.
// Round 4: bf16 everywhere.
//  - CSR build (unchanged, atomic-free gathers)
//  - cast x -> bf16 (gather table + A right half); weights -> fragment-major bf16
//  - gathers read bf16 rows (half traffic), accumulate fp32
//  - GEMMs via mfma_f32_16x16x32_bf16; B-fragments loaded directly from global
//    (fragment-major, 16B/lane coalesced); A-fragments direct 16B/lane loads;
//    epilogue staged through per-wave LDS tile for coalesced stores.
// Aliasing: h aliases xb, q aliases A1 -> ws usage ~81 MB.

#define NNODES 100000
#define NEDGES 640000

typedef __attribute__((ext_vector_type(8))) short short8v;
typedef __attribute__((ext_vector_type(4))) float f32x4;
typedef unsigned int uint;
typedef unsigned short ushort;

__device__ __forceinline__ float b2f(ushort u) {
    return __uint_as_float(((uint)u) << 16);
}
__device__ __forceinline__ ushort f2b(float f) {   // RTNE
    uint u = __float_as_uint(f);
    return (ushort)((u + 0x7fffu + ((u >> 16) & 1u)) >> 16);
}

// ---------------- CSR build ----------------

__global__ void hist_kernel(const int* __restrict__ dst, int* __restrict__ count, int E) {
    int e = blockIdx.x * blockDim.x + threadIdx.x;
    if (e < E) atomicAdd(&count[dst[e]], 1);
}

__global__ void block_sum_kernel(const int* __restrict__ count, int* __restrict__ bsum, int N) {
    __shared__ int s[256];
    int t = threadIdx.x;
    int i = blockIdx.x * 256 + t;
    s[t] = (i < N) ? count[i] : 0;
    __syncthreads();
    for (int off = 128; off > 0; off >>= 1) {
        if (t < off) s[t] += s[t + off];
        __syncthreads();
    }
    if (t == 0) bsum[blockIdx.x] = s[0];
}

__global__ void scan_bsum_kernel(int* __restrict__ bsum, int nb) {
    __shared__ int s[512];
    int t = threadIdx.x;
    int orig = (t < nb) ? bsum[t] : 0;
    s[t] = orig;
    __syncthreads();
    for (int off = 1; off < 512; off <<= 1) {
        int v = (t >= off) ? s[t - off] : 0;
        __syncthreads();
        s[t] += v;
        __syncthreads();
    }
    if (t < nb) bsum[t] = s[t] - orig;   // exclusive
}

__global__ void scan_write_kernel(const int* __restrict__ count, const int* __restrict__ bsum,
                                  int* __restrict__ rp, int N, int E) {
    __shared__ int s[256];
    int t = threadIdx.x;
    int i = blockIdx.x * 256 + t;
    int orig = (i < N) ? count[i] : 0;
    s[t] = orig;
    __syncthreads();
    for (int off = 1; off < 256; off <<= 1) {
        int v = (t >= off) ? s[t - off] : 0;
        __syncthreads();
        s[t] += v;
        __syncthreads();
    }
    if (i < N) rp[i] = bsum[blockIdx.x] + s[t] - orig;
    if (i == 0) rp[N] = E;
}

__global__ void bucket_kernel(const int* __restrict__ src, const int* __restrict__ dst,
                              const int* __restrict__ rp, int* __restrict__ cursor,
                              int* __restrict__ esrc, int E) {
    int e = blockIdx.x * blockDim.x + threadIdx.x;
    if (e >= E) return;
    int d = dst[e];
    int pos = atomicAdd(&cursor[d], 1);
    esrc[rp[d] + pos] = src[e];
}

// ---------------- casts ----------------

// x fp32 [N,128] -> xb bf16 [N,128]  and  A1[n][128:256] bf16
__global__ __launch_bounds__(256)
void cast_x_kernel(const float* __restrict__ x, ushort* __restrict__ xb,
                   ushort* __restrict__ A1, int N) {
    int i = blockIdx.x * 256 + threadIdx.x;     // N*16 threads, 8 elems each
    if (i >= N * 16) return;
    int n = i >> 4, c8 = (i & 15) * 8;
    const float* px = x + (size_t)n * 128 + c8;
    float4 v0 = *reinterpret_cast<const float4*>(px);
    float4 v1 = *reinterpret_cast<const float4*>(px + 4);
    ushort o[8];
    o[0] = f2b(v0.x); o[1] = f2b(v0.y); o[2] = f2b(v0.z); o[3] = f2b(v0.w);
    o[4] = f2b(v1.x); o[5] = f2b(v1.y); o[6] = f2b(v1.z); o[7] = f2b(v1.w);
    short8v vv = *reinterpret_cast<short8v*>(o);
    *reinterpret_cast<short8v*>(xb + (size_t)n * 128 + c8) = vv;
    *reinterpret_cast<short8v*>(A1 + (size_t)n * 256 + 128 + c8) = vv;
}

// Build fragment-major bf16 weights.
// frag f = (t*8 + g)*64 + l ; element j = B[t*32 + (l>>4)*8 + j][g*16 + (l&15)]
// mode 0 (layer1, K=256, NC=128): B[k][c] = k<128 ? P0[k*128+c] : P1[(k-128)*128+c]
// mode 1 (layer2, K=128, NC=128): B[k][c] = c<64  ? P0[k*64+c]  : P1[k*64+c-64]
__global__ __launch_bounds__(256)
void cast_w_kernel(const float* __restrict__ P0, const float* __restrict__ P1,
                   ushort* __restrict__ Wc, int K, int mode) {
    int u = blockIdx.x * 256 + threadIdx.x;
    if (u >= K * 16) return;
    int t = u >> 9;
    int g = (u >> 6) & 7;
    int l = u & 63;
    int k0 = t * 32 + ((l >> 4) * 8);
    int c = g * 16 + (l & 15);
    ushort o[8];
    #pragma unroll
    for (int j = 0; j < 8; ++j) {
        int k = k0 + j;
        float v;
        if (mode == 0) v = (k < 128) ? P0[k * 128 + c] : P1[(k - 128) * 128 + c];
        else           v = (c < 64)  ? P0[k * 64 + c]  : P1[k * 64 + (c - 64)];
        o[j] = f2b(v);
    }
    *reinterpret_cast<short8v*>(Wc + (size_t)u * 8) = *reinterpret_cast<short8v*>(o);
}

// ---------------- gathers (bf16 in, fp32 acc) ----------------

// A1[n][0:128] = mean of xb[src] rows; 16 lanes/node, 8 bf16 per lane
__global__ __launch_bounds__(256)
void gather_mean_bf16(const ushort* __restrict__ xb, const int* __restrict__ rp,
                      const int* __restrict__ esrc, ushort* __restrict__ A1, int N) {
    int gid = blockIdx.x * 256 + threadIdx.x;
    int n = gid >> 4, lane = gid & 15;
    if (n >= N) return;
    int beg = rp[n], end = rp[n + 1];
    float acc[8] = {0.f, 0.f, 0.f, 0.f, 0.f, 0.f, 0.f, 0.f};
    int j = beg;
    for (; j + 2 <= end; j += 2) {
        int s0 = esrc[j], s1 = esrc[j + 1];
        short8v v0 = *reinterpret_cast<const short8v*>(xb + (size_t)s0 * 128 + lane * 8);
        short8v v1 = *reinterpret_cast<const short8v*>(xb + (size_t)s1 * 128 + lane * 8);
        #pragma unroll
        for (int i = 0; i < 8; ++i) acc[i] += b2f((ushort)v0[i]) + b2f((ushort)v1[i]);
    }
    if (j < end) {
        int s0 = esrc[j];
        short8v v0 = *reinterpret_cast<const short8v*>(xb + (size_t)s0 * 128 + lane * 8);
        #pragma unroll
        for (int i = 0; i < 8; ++i) acc[i] += b2f((ushort)v0[i]);
    }
    float inv = 1.0f / fmaxf((float)(end - beg), 1.0f);
    ushort o[8];
    #pragma unroll
    for (int i = 0; i < 8; ++i) o[i] = f2b(acc[i] * inv);
    *reinterpret_cast<short8v*>(A1 + (size_t)n * 256 + lane * 8) = *reinterpret_cast<short8v*>(o);
}

// out[n][0:64] = mean_j q[src_j][0:64] + q[n][64:128]; 8 lanes/node; fp32 out
__global__ __launch_bounds__(256)
void gather_out64_bf16(const ushort* __restrict__ q, const int* __restrict__ rp,
                       const int* __restrict__ esrc, float* __restrict__ out, int N) {
    int gid = blockIdx.x * 256 + threadIdx.x;
    int n = gid >> 3, lane = gid & 7;
    if (n >= N) return;
    int beg = rp[n], end = rp[n + 1];
    float acc[8] = {0.f, 0.f, 0.f, 0.f, 0.f, 0.f, 0.f, 0.f};
    int j = beg;
    for (; j + 2 <= end; j += 2) {
        int s0 = esrc[j], s1 = esrc[j + 1];
        short8v v0 = *reinterpret_cast<const short8v*>(q + (size_t)s0 * 128 + lane * 8);
        short8v v1 = *reinterpret_cast<const short8v*>(q + (size_t)s1 * 128 + lane * 8);
        #pragma unroll
        for (int i = 0; i < 8; ++i) acc[i] += b2f((ushort)v0[i]) + b2f((ushort)v1[i]);
    }
    if (j < end) {
        int s0 = esrc[j];
        short8v v0 = *reinterpret_cast<const short8v*>(q + (size_t)s0 * 128 + lane * 8);
        #pragma unroll
        for (int i = 0; i < 8; ++i) acc[i] += b2f((ushort)v0[i]);
    }
    float inv = 1.0f / fmaxf((float)(end - beg), 1.0f);
    short8v sv = *reinterpret_cast<const short8v*>(q + (size_t)n * 128 + 64 + lane * 8);
    float o[8];
    #pragma unroll
    for (int i = 0; i < 8; ++i) o[i] = acc[i] * inv + b2f((ushort)sv[i]);
    float* po = out + (size_t)n * 64 + lane * 8;
    *reinterpret_cast<float4*>(po)     = make_float4(o[0], o[1], o[2], o[3]);
    *reinterpret_cast<float4*>(po + 4) = make_float4(o[4], o[5], o[6], o[7]);
}

// ---------------- MFMA GEMM: C[M,128] = A[M,K] @ B[K,128] (+bias, relu) ----------------
// 4 waves/block, 32 rows/wave (2 row-frags), all 128 cols (8 col-frags).
// A frag: lane l holds A[row0 + (l&15)][t*32 + (l>>4)*8 .. +8] (16B contiguous).
// B frag: fragment-major Wc, wf = Wc + ((t*8+g)*64 + l)*8 (16B contiguous/lane).
// C/D: col = g*16 + (l&15), row = (l>>4)*4 + j.
// BMODE 0: +bias[col] ; BMODE 1: +((col>=64) ? bias[col-64] : 0)
template<int K, int BMODE, bool RELU>
__global__ __launch_bounds__(256)
void mfma_gemm_kernel(const ushort* __restrict__ A, const ushort* __restrict__ Wc,
                      const float* __restrict__ bias, ushort* __restrict__ C, int N)
{
    __shared__ ushort cbuf[4][32][128];   // 32 KB
    const int wid = threadIdx.x >> 6;
    const int l = threadIdx.x & 63;
    const int row0 = blockIdx.x * 128 + wid * 32;
    const int ar = l & 15;
    const int ak = (l >> 4) * 8;

    f32x4 zz = {0.f, 0.f, 0.f, 0.f};
    f32x4 acc[2][8];
    #pragma unroll
    for (int g = 0; g < 8; ++g) { acc[0][g] = zz; acc[1][g] = zz; }

    const int rA0 = row0 + ar;
    const int rA1 = row0 + 16 + ar;
    const bool v0 = rA0 < N, v1 = rA1 < N;
    const ushort* a0p = A + (size_t)rA0 * K + ak;
    const ushort* a1p = A + (size_t)rA1 * K + ak;
    const short8v* wbase = reinterpret_cast<const short8v*>(Wc);
    short8v az = {0, 0, 0, 0, 0, 0, 0, 0};

    #pragma unroll
    for (int t = 0; t < K / 32; ++t) {
        short8v af0 = az, af1 = az;
        if (v0) af0 = *reinterpret_cast<const short8v*>(a0p + t * 32);
        if (v1) af1 = *reinterpret_cast<const short8v*>(a1p + t * 32);
        const short8v* wf = wbase + (size_t)(t * 8) * 64 + l;
        #pragma unroll
        for (int g = 0; g < 8; ++g) {
            short8v bf = wf[g * 64];
            acc[0][g] = __builtin_amdgcn_mfma_f32_16x16x32_bf16(af0, bf, acc[0][g], 0, 0, 0);
            acc[1][g] = __builtin_amdgcn_mfma_f32_16x16x32_bf16(af1, bf, acc[1][g], 0, 0, 0);
        }
    }

    // epilogue -> LDS tile (bias + relu + bf16 cvt)
    const int cr4 = (l >> 4) * 4;
    const int cc = l & 15;
    #pragma unroll
    for (int g = 0; g < 8; ++g) {
        int col = g * 16 + cc;
        float bv = (BMODE == 0) ? bias[col] : ((col >= 64) ? bias[col - 64] : 0.f);
        #pragma unroll
        for (int j = 0; j < 4; ++j) {
            float u0 = acc[0][g][j] + bv;
            float u1 = acc[1][g][j] + bv;
            if (RELU) { u0 = fmaxf(u0, 0.f); u1 = fmaxf(u1, 0.f); }
            cbuf[wid][cr4 + j][col]      = f2b(u0);
            cbuf[wid][16 + cr4 + j][col] = f2b(u1);
        }
    }
    __syncthreads();

    // coalesced store: 32 rows x 16 short8/row = 512 frags, 64 lanes -> 8 passes
    const ushort* cf = &cbuf[wid][0][0];
    #pragma unroll
    for (int p = 0; p < 8; ++p) {
        int idx = p * 64 + l;
        int fr = idx >> 4;
        int r = row0 + fr;
        if (r < N)
            *reinterpret_cast<short8v*>(C + (size_t)r * 128 + (idx & 15) * 8) =
                *reinterpret_cast<const short8v*>(cf + idx * 8);
    }
}

// ---------------- launch ----------------

extern "C" void kernel_launch(void* const* d_in, const int* in_sizes, int n_in,
                              void* d_out, int out_size, void* d_ws, size_t ws_size,
                              hipStream_t stream)
{
    const float* x   = (const float*)d_in[0];
    const int*   ei  = (const int*)d_in[1];
    const float* W1l = (const float*)d_in[2];
    const float* b1  = (const float*)d_in[3];
    const float* W1r = (const float*)d_in[4];
    const float* W2l = (const float*)d_in[5];
    const float* b2  = (const float*)d_in[6];
    const float* W2r = (const float*)d_in[7];
    float* out = (float*)d_out;

    const int N = NNODES, E = NEDGES;
    const int* src = ei;
    const int* dst = ei + E;

    char* ws = (char*)d_ws;
    // ints: ~3.77 MB
    int* count  = (int*)ws;                 // N
    int* cursor = count + N;                // N
    int* rp     = cursor + N;               // N+1
    int* bsum   = rp + N + 1;               // 512
    int* esrc   = bsum + 512;               // E
    // bf16 buffers from 4 MB
    const size_t MB = 1024u * 1024u;
    ushort* Wc1 = (ushort*)(ws + 4 * MB);                   // 256*128 = 64 KB
    ushort* Wc2 = (ushort*)(ws + 4 * MB + 64 * 1024);       // 128*128 = 32 KB
    ushort* A1  = (ushort*)(ws + 4 * MB + 128 * 1024);      // N*256*2 = 51.2 MB (later: q)
    ushort* xb  = A1 + (size_t)N * 256;                     // N*128*2 = 25.6 MB (later: h)
    ushort* h = xb;      // alias: xb dead after gather_mean
    ushort* q = A1;      // alias: A1 dead after gemm1

    const int nb = (N + 255) / 256;

    hipMemsetAsync(ws, 0, (size_t)2 * N * 4, stream);   // count + cursor

    // CSR build
    hist_kernel<<<(E + 255) / 256, 256, 0, stream>>>(dst, count, E);
    block_sum_kernel<<<nb, 256, 0, stream>>>(count, bsum, N);
    scan_bsum_kernel<<<1, 512, 0, stream>>>(bsum, nb);
    scan_write_kernel<<<nb, 256, 0, stream>>>(count, bsum, rp, N, E);
    bucket_kernel<<<(E + 255) / 256, 256, 0, stream>>>(src, dst, rp, cursor, esrc, E);

    // casts
    cast_x_kernel<<<(N * 16 + 255) / 256, 256, 0, stream>>>(x, xb, A1, N);
    cast_w_kernel<<<(256 * 16 + 255) / 256, 256, 0, stream>>>(W1l, W1r, Wc1, 256, 0);
    cast_w_kernel<<<(128 * 16 + 255) / 256, 256, 0, stream>>>(W2l, W2r, Wc2, 128, 1);

    // layer 1
    gather_mean_bf16<<<(N * 16 + 255) / 256, 256, 0, stream>>>(xb, rp, esrc, A1, N);
    mfma_gemm_kernel<256, 0, true><<<(N + 127) / 128, 256, 0, stream>>>(A1, Wc1, b1, h, N);

    // layer 2 (transform-first)
    mfma_gemm_kernel<128, 1, false><<<(N + 127) / 128, 256, 0, stream>>>(h, Wc2, b2, q, N);
    gather_out64_bf16<<<(N * 8 + 255) / 256, 256, 0, stream>>>(q, rp, esrc, out, N);
}

// Round 8
// 262.974 us; speedup vs baseline: 9.6335x; 1.0246x over previous
//
#include <hip/hip_runtime.h>
#include <hip/hip_bf16.h>

// GraphSAGE 2-layer, N=100000, E=640000, d=128 -> 128 -> 64.
// Round 5 (3rd resubmit; broker timeouts): fuse gemm1+gemm2 (kill 51 MB h
// round-trip); fuse cast_x/hist/cast_w into one prep kernel. Padded LDS tile
// [32][136] for conflict-free stage-2 A-fragment ds_read_b128. q no longer
// aliases A1 (fused kernel reads A1 while writing q). ws ~107 MB of 256 MiB.

#define NNODES 100000
#define NEDGES 640000

typedef __attribute__((ext_vector_type(8))) short short8v;
typedef __attribute__((ext_vector_type(4))) float f32x4;
typedef unsigned int uint;
typedef unsigned short ushort;

__device__ __forceinline__ float b2f(ushort u) {
    return __uint_as_float(((uint)u) << 16);
}
__device__ __forceinline__ ushort f2b(float f) {   // RTNE
    uint u = __float_as_uint(f);
    return (ushort)((u + 0x7fffu + ((u >> 16) & 1u)) >> 16);
}

// ---------------- CSR build ----------------

__global__ void block_sum_kernel(const int* __restrict__ count, int* __restrict__ bsum, int N) {
    __shared__ int s[256];
    int t = threadIdx.x;
    int i = blockIdx.x * 256 + t;
    s[t] = (i < N) ? count[i] : 0;
    __syncthreads();
    for (int off = 128; off > 0; off >>= 1) {
        if (t < off) s[t] += s[t + off];
        __syncthreads();
    }
    if (t == 0) bsum[blockIdx.x] = s[0];
}

__global__ void scan_bsum_kernel(int* __restrict__ bsum, int nb) {
    __shared__ int s[512];
    int t = threadIdx.x;
    int orig = (t < nb) ? bsum[t] : 0;
    s[t] = orig;
    __syncthreads();
    for (int off = 1; off < 512; off <<= 1) {
        int v = (t >= off) ? s[t - off] : 0;
        __syncthreads();
        s[t] += v;
        __syncthreads();
    }
    if (t < nb) bsum[t] = s[t] - orig;   // exclusive
}

__global__ void scan_write_kernel(const int* __restrict__ count, const int* __restrict__ bsum,
                                  int* __restrict__ rp, int N, int E) {
    __shared__ int s[256];
    int t = threadIdx.x;
    int i = blockIdx.x * 256 + t;
    int orig = (i < N) ? count[i] : 0;
    s[t] = orig;
    __syncthreads();
    for (int off = 1; off < 256; off <<= 1) {
        int v = (t >= off) ? s[t - off] : 0;
        __syncthreads();
        s[t] += v;
        __syncthreads();
    }
    if (i < N) rp[i] = bsum[blockIdx.x] + s[t] - orig;
    if (i == 0) rp[N] = E;
}

__global__ void bucket_kernel(const int* __restrict__ src, const int* __restrict__ dst,
                              const int* __restrict__ rp, int* __restrict__ cursor,
                              int* __restrict__ esrc, int E) {
    int e = blockIdx.x * blockDim.x + threadIdx.x;
    if (e >= E) return;
    int d = dst[e];
    int pos = atomicAdd(&cursor[d], 1);
    esrc[rp[d] + pos] = src[e];
}

// ---------------- prep: cast_x + hist + cast_w1 + cast_w2 ----------------
// Fragment-major bf16 weights:
// frag f = (t*8 + g)*64 + l ; element j = B[t*32 + (l>>4)*8 + j][g*16 + (l&15)]
// W1 (K=256, NC=128): B[k][c] = k<128 ? W1l[k*128+c] : W1r[(k-128)*128+c]
// W2 (K=128, NC=128): B[k][c] = c<64  ? W2l[k*64+c]  : W2r[k*64+c-64]
__global__ __launch_bounds__(256)
void prep_kernel(const float* __restrict__ x, ushort* __restrict__ xb, ushort* __restrict__ A1,
                 const int* __restrict__ dst, int* __restrict__ count,
                 const float* __restrict__ W1l, const float* __restrict__ W1r, ushort* __restrict__ Wc1,
                 const float* __restrict__ W2l, const float* __restrict__ W2r, ushort* __restrict__ Wc2,
                 int N, int E)
{
    int i = blockIdx.x * 256 + threadIdx.x;

    if (i < N * 16) {   // cast x -> xb and A1 right half
        int n = i >> 4, c8 = (i & 15) * 8;
        const float* px = x + (size_t)n * 128 + c8;
        float4 v0 = *reinterpret_cast<const float4*>(px);
        float4 v1 = *reinterpret_cast<const float4*>(px + 4);
        ushort o[8];
        o[0] = f2b(v0.x); o[1] = f2b(v0.y); o[2] = f2b(v0.z); o[3] = f2b(v0.w);
        o[4] = f2b(v1.x); o[5] = f2b(v1.y); o[6] = f2b(v1.z); o[7] = f2b(v1.w);
        short8v vv = *reinterpret_cast<short8v*>(o);
        *reinterpret_cast<short8v*>(xb + (size_t)n * 128 + c8) = vv;
        *reinterpret_cast<short8v*>(A1 + (size_t)n * 256 + 128 + c8) = vv;
    }

    if (i < E) atomicAdd(&count[dst[i]], 1);   // hist

    if (i < 256 * 16) {   // W1 fragments
        int u = i;
        int t = u >> 9, g = (u >> 6) & 7, l = u & 63;
        int k0 = t * 32 + ((l >> 4) * 8);
        int c = g * 16 + (l & 15);
        ushort o[8];
        #pragma unroll
        for (int j = 0; j < 8; ++j) {
            int k = k0 + j;
            float v = (k < 128) ? W1l[k * 128 + c] : W1r[(k - 128) * 128 + c];
            o[j] = f2b(v);
        }
        *reinterpret_cast<short8v*>(Wc1 + (size_t)u * 8) = *reinterpret_cast<short8v*>(o);
    } else if (i < 256 * 16 + 128 * 16) {   // W2 fragments
        int u = i - 256 * 16;
        int t = u >> 9, g = (u >> 6) & 7, l = u & 63;
        int k0 = t * 32 + ((l >> 4) * 8);
        int c = g * 16 + (l & 15);
        ushort o[8];
        #pragma unroll
        for (int j = 0; j < 8; ++j) {
            int k = k0 + j;
            float v = (c < 64) ? W2l[k * 64 + c] : W2r[k * 64 + (c - 64)];
            o[j] = f2b(v);
        }
        *reinterpret_cast<short8v*>(Wc2 + (size_t)u * 8) = *reinterpret_cast<short8v*>(o);
    }
}

// ---------------- gathers (bf16 in, fp32 acc) ----------------

__global__ __launch_bounds__(256)
void gather_mean_bf16(const ushort* __restrict__ xb, const int* __restrict__ rp,
                      const int* __restrict__ esrc, ushort* __restrict__ A1, int N) {
    int gid = blockIdx.x * 256 + threadIdx.x;
    int n = gid >> 4, lane = gid & 15;
    if (n >= N) return;
    int beg = rp[n], end = rp[n + 1];
    float acc[8] = {0.f, 0.f, 0.f, 0.f, 0.f, 0.f, 0.f, 0.f};
    int j = beg;
    for (; j + 2 <= end; j += 2) {
        int s0 = esrc[j], s1 = esrc[j + 1];
        short8v v0 = *reinterpret_cast<const short8v*>(xb + (size_t)s0 * 128 + lane * 8);
        short8v v1 = *reinterpret_cast<const short8v*>(xb + (size_t)s1 * 128 + lane * 8);
        #pragma unroll
        for (int i = 0; i < 8; ++i) acc[i] += b2f((ushort)v0[i]) + b2f((ushort)v1[i]);
    }
    if (j < end) {
        int s0 = esrc[j];
        short8v v0 = *reinterpret_cast<const short8v*>(xb + (size_t)s0 * 128 + lane * 8);
        #pragma unroll
        for (int i = 0; i < 8; ++i) acc[i] += b2f((ushort)v0[i]);
    }
    float inv = 1.0f / fmaxf((float)(end - beg), 1.0f);
    ushort o[8];
    #pragma unroll
    for (int i = 0; i < 8; ++i) o[i] = f2b(acc[i] * inv);
    *reinterpret_cast<short8v*>(A1 + (size_t)n * 256 + lane * 8) = *reinterpret_cast<short8v*>(o);
}

__global__ __launch_bounds__(256)
void gather_out64_bf16(const ushort* __restrict__ q, const int* __restrict__ rp,
                       const int* __restrict__ esrc, float* __restrict__ out, int N) {
    int gid = blockIdx.x * 256 + threadIdx.x;
    int n = gid >> 3, lane = gid & 7;
    if (n >= N) return;
    int beg = rp[n], end = rp[n + 1];
    float acc[8] = {0.f, 0.f, 0.f, 0.f, 0.f, 0.f, 0.f, 0.f};
    int j = beg;
    for (; j + 2 <= end; j += 2) {
        int s0 = esrc[j], s1 = esrc[j + 1];
        short8v v0 = *reinterpret_cast<const short8v*>(q + (size_t)s0 * 128 + lane * 8);
        short8v v1 = *reinterpret_cast<const short8v*>(q + (size_t)s1 * 128 + lane * 8);
        #pragma unroll
        for (int i = 0; i < 8; ++i) acc[i] += b2f((ushort)v0[i]) + b2f((ushort)v1[i]);
    }
    if (j < end) {
        int s0 = esrc[j];
        short8v v0 = *reinterpret_cast<const short8v*>(q + (size_t)s0 * 128 + lane * 8);
        #pragma unroll
        for (int i = 0; i < 8; ++i) acc[i] += b2f((ushort)v0[i]);
    }
    float inv = 1.0f / fmaxf((float)(end - beg), 1.0f);
    short8v sv = *reinterpret_cast<const short8v*>(q + (size_t)n * 128 + 64 + lane * 8);
    float o[8];
    #pragma unroll
    for (int i = 0; i < 8; ++i) o[i] = acc[i] * inv + b2f((ushort)sv[i]);
    float* po = out + (size_t)n * 64 + lane * 8;
    *reinterpret_cast<float4*>(po)     = make_float4(o[0], o[1], o[2], o[3]);
    *reinterpret_cast<float4*>(po + 4) = make_float4(o[4], o[5], o[6], o[7]);
}

// ---------------- fused double GEMM ----------------
// Per wave: 32 rows. Stage 1: h = relu(A1[32,256] @ Wc1 + b1) -> LDS tile [32][136] bf16.
// Stage 2: q = h @ Wc2 (+b2 on cols 64..127) -> LDS -> coalesced global store.
// A frag (stage1, global): lane l holds A1[row0+(l&15)(+16)][t*32+(l>>4)*8 ..+8].
// A frag (stage2, LDS):    same pattern from hbuf, padded stride 136 (bank-conflict-free).
// C/D: col = g*16 + (l&15), row = (l>>4)*4 + j (+16 for second row-frag).
__global__ __launch_bounds__(256)
void fused_gemm_kernel(const ushort* __restrict__ A1, const ushort* __restrict__ Wc1,
                       const float* __restrict__ b1, const ushort* __restrict__ Wc2,
                       const float* __restrict__ b2, ushort* __restrict__ q, int N)
{
    __shared__ ushort hbuf[4][32][136];   // 34 KB, padded: +8 ushorts = +16B/row
    const int wid = threadIdx.x >> 6;
    const int l = threadIdx.x & 63;
    const int row0 = blockIdx.x * 128 + wid * 32;
    const int ar = l & 15;
    const int ak = (l >> 4) * 8;

    f32x4 zz = {0.f, 0.f, 0.f, 0.f};
    f32x4 acc[2][8];
    #pragma unroll
    for (int g = 0; g < 8; ++g) { acc[0][g] = zz; acc[1][g] = zz; }

    // ---- stage 1: K=256 from global A1 ----
    {
        const int rA0 = row0 + ar;
        const int rA1 = row0 + 16 + ar;
        const bool v0 = rA0 < N, v1 = rA1 < N;
        const ushort* a0p = A1 + (size_t)rA0 * 256 + ak;
        const ushort* a1p = A1 + (size_t)rA1 * 256 + ak;
        const short8v* wbase = reinterpret_cast<const short8v*>(Wc1);
        short8v az = {0, 0, 0, 0, 0, 0, 0, 0};
        #pragma unroll
        for (int t = 0; t < 8; ++t) {
            short8v af0 = az, af1 = az;
            if (v0) af0 = *reinterpret_cast<const short8v*>(a0p + t * 32);
            if (v1) af1 = *reinterpret_cast<const short8v*>(a1p + t * 32);
            const short8v* wf = wbase + (size_t)(t * 8) * 64 + l;
            #pragma unroll
            for (int g = 0; g < 8; ++g) {
                short8v bf = wf[g * 64];
                acc[0][g] = __builtin_amdgcn_mfma_f32_16x16x32_bf16(af0, bf, acc[0][g], 0, 0, 0);
                acc[1][g] = __builtin_amdgcn_mfma_f32_16x16x32_bf16(af1, bf, acc[1][g], 0, 0, 0);
            }
        }
    }

    // ---- epilogue 1: bias + relu -> bf16 -> hbuf ----
    {
        const int cr4 = (l >> 4) * 4;
        const int cc = l & 15;
        #pragma unroll
        for (int g = 0; g < 8; ++g) {
            int col = g * 16 + cc;
            float bv = b1[col];
            #pragma unroll
            for (int j = 0; j < 4; ++j) {
                hbuf[wid][cr4 + j][col]      = f2b(fmaxf(acc[0][g][j] + bv, 0.f));
                hbuf[wid][16 + cr4 + j][col] = f2b(fmaxf(acc[1][g][j] + bv, 0.f));
            }
        }
    }
    // same-wave LDS RAW: DS pipe is in-order per wave; compiler inserts lgkmcnt.

    // ---- stage 2: K=128 from LDS hbuf ----
    #pragma unroll
    for (int g = 0; g < 8; ++g) { acc[0][g] = zz; acc[1][g] = zz; }
    {
        const short8v* wbase = reinterpret_cast<const short8v*>(Wc2);
        #pragma unroll
        for (int t = 0; t < 4; ++t) {
            short8v af0 = *reinterpret_cast<const short8v*>(&hbuf[wid][ar][t * 32 + ak]);
            short8v af1 = *reinterpret_cast<const short8v*>(&hbuf[wid][16 + ar][t * 32 + ak]);
            const short8v* wf = wbase + (size_t)(t * 8) * 64 + l;
            #pragma unroll
            for (int g = 0; g < 8; ++g) {
                short8v bf = wf[g * 64];
                acc[0][g] = __builtin_amdgcn_mfma_f32_16x16x32_bf16(af0, bf, acc[0][g], 0, 0, 0);
                acc[1][g] = __builtin_amdgcn_mfma_f32_16x16x32_bf16(af1, bf, acc[1][g], 0, 0, 0);
            }
        }
    }

    // ---- epilogue 2: +b2 on cols>=64 -> bf16 -> hbuf (overwrite) ----
    {
        const int cr4 = (l >> 4) * 4;
        const int cc = l & 15;
        #pragma unroll
        for (int g = 0; g < 8; ++g) {
            int col = g * 16 + cc;
            float bv = (col >= 64) ? b2[col - 64] : 0.f;
            #pragma unroll
            for (int j = 0; j < 4; ++j) {
                hbuf[wid][cr4 + j][col]      = f2b(acc[0][g][j] + bv);
                hbuf[wid][16 + cr4 + j][col] = f2b(acc[1][g][j] + bv);
            }
        }
    }

    // ---- coalesced store: 32 rows x 16 short8 = 512 frags, 8 passes ----
    #pragma unroll
    for (int p = 0; p < 8; ++p) {
        int idx = p * 64 + l;
        int fr = idx >> 4;
        int c8 = idx & 15;
        int r = row0 + fr;
        if (r < N)
            *reinterpret_cast<short8v*>(q + (size_t)r * 128 + c8 * 8) =
                *reinterpret_cast<const short8v*>(&hbuf[wid][fr][c8 * 8]);
    }
}

// ---------------- launch ----------------

extern "C" void kernel_launch(void* const* d_in, const int* in_sizes, int n_in,
                              void* d_out, int out_size, void* d_ws, size_t ws_size,
                              hipStream_t stream)
{
    const float* x   = (const float*)d_in[0];
    const int*   ei  = (const int*)d_in[1];
    const float* W1l = (const float*)d_in[2];
    const float* b1  = (const float*)d_in[3];
    const float* W1r = (const float*)d_in[4];
    const float* W2l = (const float*)d_in[5];
    const float* b2  = (const float*)d_in[6];
    const float* W2r = (const float*)d_in[7];
    float* out = (float*)d_out;

    const int N = NNODES, E = NEDGES;
    const int* src = ei;
    const int* dst = ei + E;

    char* ws = (char*)d_ws;
    // ints: < 4 MB
    int* count  = (int*)ws;                 // N
    int* cursor = count + N;                // N
    int* rp     = cursor + N;               // N+1
    int* bsum   = rp + N + 1;               // 512
    int* esrc   = bsum + 512;               // E
    // bf16 buffers from 4 MB (ws_size = 256 MiB per harness fill)
    const size_t MB = 1024u * 1024u;
    ushort* Wc1 = (ushort*)(ws + 4 * MB);                   // 256*128*2 = 64 KB
    ushort* Wc2 = (ushort*)(ws + 4 * MB + 64 * 1024);       // 128*128*2 = 32 KB
    ushort* A1  = (ushort*)(ws + 4 * MB + 128 * 1024);      // N*256*2 = 51.2 MB
    ushort* xb  = A1 + (size_t)N * 256;                     // N*128*2 = 25.6 MB
    ushort* q   = xb + (size_t)N * 128;                     // N*128*2 = 25.6 MB (no alias!)

    const int nb = (N + 255) / 256;

    hipMemsetAsync(ws, 0, (size_t)2 * N * 4, stream);   // count + cursor

    // prep: cast_x + hist + cast_w (fused)
    prep_kernel<<<(N * 16 + 255) / 256, 256, 0, stream>>>(
        x, xb, A1, dst, count, W1l, W1r, Wc1, W2l, W2r, Wc2, N, E);

    // CSR scan + bucket
    block_sum_kernel<<<nb, 256, 0, stream>>>(count, bsum, N);
    scan_bsum_kernel<<<1, 512, 0, stream>>>(bsum, nb);
    scan_write_kernel<<<nb, 256, 0, stream>>>(count, bsum, rp, N, E);
    bucket_kernel<<<(E + 255) / 256, 256, 0, stream>>>(src, dst, rp, cursor, esrc, E);

    // layer 1 gather, then fused (layer1 GEMM + layer2 transform) in one kernel
    gather_mean_bf16<<<(N * 16 + 255) / 256, 256, 0, stream>>>(xb, rp, esrc, A1, N);
    fused_gemm_kernel<<<(N + 127) / 128, 256, 0, stream>>>(A1, Wc1, b1, Wc2, b2, q, N);

    // layer 2 gather + self add -> fp32 out
    gather_out64_bf16<<<(N * 8 + 255) / 256, 256, 0, stream>>>(q, rp, esrc, out, N);
}

// Round 9
// 261.905 us; speedup vs baseline: 9.6728x; 1.0041x over previous
//
#include <hip/hip_runtime.h>
#include <hip/hip_bf16.h>

// GraphSAGE 2-layer, N=100000, E=640000, d=128 -> 128 -> 64.
// Round 9: prep was latency-bound at 42us with a redundant 25.6MB write.
//  - cast_x: pure streaming, 64B/thread, writes ONLY xb (A1-dup removed)
//  - fused_gemm stage-1 reads mean[N,128] (t<4) + xb[N,128] (t>=4) directly
//  - hist + weight-casts in their own small kernel (profile isolation)

#define NNODES 100000
#define NEDGES 640000

typedef __attribute__((ext_vector_type(8))) short short8v;
typedef __attribute__((ext_vector_type(4))) float f32x4;
typedef unsigned int uint;
typedef unsigned short ushort;

__device__ __forceinline__ float b2f(ushort u) {
    return __uint_as_float(((uint)u) << 16);
}
__device__ __forceinline__ ushort f2b(float f) {   // RTNE
    uint u = __float_as_uint(f);
    return (ushort)((u + 0x7fffu + ((u >> 16) & 1u)) >> 16);
}

// ---------------- streaming cast: x fp32 -> xb bf16 (64B in / 32B out per thread) ----------------

__global__ __launch_bounds__(256)
void cast_x_kernel(const float* __restrict__ x, ushort* __restrict__ xb, int N) {
    int i = blockIdx.x * 256 + threadIdx.x;      // N*8 units, 16 floats each
    if (i >= N * 8) return;
    const float* px = x + (size_t)i * 16;
    float4 v0 = *reinterpret_cast<const float4*>(px);
    float4 v1 = *reinterpret_cast<const float4*>(px + 4);
    float4 v2 = *reinterpret_cast<const float4*>(px + 8);
    float4 v3 = *reinterpret_cast<const float4*>(px + 12);
    ushort o[16];
    o[0]=f2b(v0.x); o[1]=f2b(v0.y); o[2]=f2b(v0.z); o[3]=f2b(v0.w);
    o[4]=f2b(v1.x); o[5]=f2b(v1.y); o[6]=f2b(v1.z); o[7]=f2b(v1.w);
    o[8]=f2b(v2.x); o[9]=f2b(v2.y); o[10]=f2b(v2.z); o[11]=f2b(v2.w);
    o[12]=f2b(v3.x); o[13]=f2b(v3.y); o[14]=f2b(v3.z); o[15]=f2b(v3.w);
    ushort* po = xb + (size_t)i * 16;
    *reinterpret_cast<short8v*>(po)     = *reinterpret_cast<short8v*>(o);
    *reinterpret_cast<short8v*>(po + 8) = *reinterpret_cast<short8v*>(o + 8);
}

// ---------------- hist + fragment-major weight casts ----------------
// frag f = (t*8 + g)*64 + l ; element j = B[t*32 + (l>>4)*8 + j][g*16 + (l&15)]
// W1 (K=256): B[k][c] = k<128 ? W1l[k*128+c] : W1r[(k-128)*128+c]
// W2 (K=128): B[k][c] = c<64  ? W2l[k*64+c]  : W2r[k*64+c-64]
__global__ __launch_bounds__(256)
void hist_wcast_kernel(const int* __restrict__ dst, int* __restrict__ count,
                       const float* __restrict__ W1l, const float* __restrict__ W1r,
                       ushort* __restrict__ Wc1,
                       const float* __restrict__ W2l, const float* __restrict__ W2r,
                       ushort* __restrict__ Wc2, int E)
{
    int i = blockIdx.x * 256 + threadIdx.x;
    if (i < E) atomicAdd(&count[dst[i]], 1);

    if (i < 256 * 16) {   // W1 fragments (4096 threads)
        int u = i;
        int t = u >> 9, g = (u >> 6) & 7, l = u & 63;
        int k0 = t * 32 + ((l >> 4) * 8);
        int c = g * 16 + (l & 15);
        ushort o[8];
        #pragma unroll
        for (int j = 0; j < 8; ++j) {
            int k = k0 + j;
            float v = (k < 128) ? W1l[k * 128 + c] : W1r[(k - 128) * 128 + c];
            o[j] = f2b(v);
        }
        *reinterpret_cast<short8v*>(Wc1 + (size_t)u * 8) = *reinterpret_cast<short8v*>(o);
    } else if (i < 256 * 16 + 128 * 16) {   // W2 fragments (2048 threads)
        int u = i - 256 * 16;
        int t = u >> 9, g = (u >> 6) & 7, l = u & 63;
        int k0 = t * 32 + ((l >> 4) * 8);
        int c = g * 16 + (l & 15);
        ushort o[8];
        #pragma unroll
        for (int j = 0; j < 8; ++j) {
            int k = k0 + j;
            float v = (c < 64) ? W2l[k * 64 + c] : W2r[k * 64 + (c - 64)];
            o[j] = f2b(v);
        }
        *reinterpret_cast<short8v*>(Wc2 + (size_t)u * 8) = *reinterpret_cast<short8v*>(o);
    }
}

// ---------------- CSR scan + bucket ----------------

__global__ void block_sum_kernel(const int* __restrict__ count, int* __restrict__ bsum, int N) {
    __shared__ int s[256];
    int t = threadIdx.x;
    int i = blockIdx.x * 256 + t;
    s[t] = (i < N) ? count[i] : 0;
    __syncthreads();
    for (int off = 128; off > 0; off >>= 1) {
        if (t < off) s[t] += s[t + off];
        __syncthreads();
    }
    if (t == 0) bsum[blockIdx.x] = s[0];
}

__global__ void scan_bsum_kernel(int* __restrict__ bsum, int nb) {
    __shared__ int s[512];
    int t = threadIdx.x;
    int orig = (t < nb) ? bsum[t] : 0;
    s[t] = orig;
    __syncthreads();
    for (int off = 1; off < 512; off <<= 1) {
        int v = (t >= off) ? s[t - off] : 0;
        __syncthreads();
        s[t] += v;
        __syncthreads();
    }
    if (t < nb) bsum[t] = s[t] - orig;   // exclusive
}

__global__ void scan_write_kernel(const int* __restrict__ count, const int* __restrict__ bsum,
                                  int* __restrict__ rp, int N, int E) {
    __shared__ int s[256];
    int t = threadIdx.x;
    int i = blockIdx.x * 256 + t;
    int orig = (i < N) ? count[i] : 0;
    s[t] = orig;
    __syncthreads();
    for (int off = 1; off < 256; off <<= 1) {
        int v = (t >= off) ? s[t - off] : 0;
        __syncthreads();
        s[t] += v;
        __syncthreads();
    }
    if (i < N) rp[i] = bsum[blockIdx.x] + s[t] - orig;
    if (i == 0) rp[N] = E;
}

__global__ void bucket_kernel(const int* __restrict__ src, const int* __restrict__ dst,
                              const int* __restrict__ rp, int* __restrict__ cursor,
                              int* __restrict__ esrc, int E) {
    int e = blockIdx.x * blockDim.x + threadIdx.x;
    if (e >= E) return;
    int d = dst[e];
    int pos = atomicAdd(&cursor[d], 1);
    esrc[rp[d] + pos] = src[e];
}

// ---------------- gathers (bf16 in, fp32 acc) ----------------

__global__ __launch_bounds__(256)
void gather_mean_bf16(const ushort* __restrict__ xb, const int* __restrict__ rp,
                      const int* __restrict__ esrc, ushort* __restrict__ mean, int N) {
    int gid = blockIdx.x * 256 + threadIdx.x;
    int n = gid >> 4, lane = gid & 15;
    if (n >= N) return;
    int beg = rp[n], end = rp[n + 1];
    float acc[8] = {0.f, 0.f, 0.f, 0.f, 0.f, 0.f, 0.f, 0.f};
    int j = beg;
    for (; j + 2 <= end; j += 2) {
        int s0 = esrc[j], s1 = esrc[j + 1];
        short8v v0 = *reinterpret_cast<const short8v*>(xb + (size_t)s0 * 128 + lane * 8);
        short8v v1 = *reinterpret_cast<const short8v*>(xb + (size_t)s1 * 128 + lane * 8);
        #pragma unroll
        for (int i = 0; i < 8; ++i) acc[i] += b2f((ushort)v0[i]) + b2f((ushort)v1[i]);
    }
    if (j < end) {
        int s0 = esrc[j];
        short8v v0 = *reinterpret_cast<const short8v*>(xb + (size_t)s0 * 128 + lane * 8);
        #pragma unroll
        for (int i = 0; i < 8; ++i) acc[i] += b2f((ushort)v0[i]);
    }
    float inv = 1.0f / fmaxf((float)(end - beg), 1.0f);
    ushort o[8];
    #pragma unroll
    for (int i = 0; i < 8; ++i) o[i] = f2b(acc[i] * inv);
    *reinterpret_cast<short8v*>(mean + (size_t)n * 128 + lane * 8) = *reinterpret_cast<short8v*>(o);
}

__global__ __launch_bounds__(256)
void gather_out64_bf16(const ushort* __restrict__ q, const int* __restrict__ rp,
                       const int* __restrict__ esrc, float* __restrict__ out, int N) {
    int gid = blockIdx.x * 256 + threadIdx.x;
    int n = gid >> 3, lane = gid & 7;
    if (n >= N) return;
    int beg = rp[n], end = rp[n + 1];
    float acc[8] = {0.f, 0.f, 0.f, 0.f, 0.f, 0.f, 0.f, 0.f};
    int j = beg;
    for (; j + 2 <= end; j += 2) {
        int s0 = esrc[j], s1 = esrc[j + 1];
        short8v v0 = *reinterpret_cast<const short8v*>(q + (size_t)s0 * 128 + lane * 8);
        short8v v1 = *reinterpret_cast<const short8v*>(q + (size_t)s1 * 128 + lane * 8);
        #pragma unroll
        for (int i = 0; i < 8; ++i) acc[i] += b2f((ushort)v0[i]) + b2f((ushort)v1[i]);
    }
    if (j < end) {
        int s0 = esrc[j];
        short8v v0 = *reinterpret_cast<const short8v*>(q + (size_t)s0 * 128 + lane * 8);
        #pragma unroll
        for (int i = 0; i < 8; ++i) acc[i] += b2f((ushort)v0[i]);
    }
    float inv = 1.0f / fmaxf((float)(end - beg), 1.0f);
    short8v sv = *reinterpret_cast<const short8v*>(q + (size_t)n * 128 + 64 + lane * 8);
    float o[8];
    #pragma unroll
    for (int i = 0; i < 8; ++i) o[i] = acc[i] * inv + b2f((ushort)sv[i]);
    float* po = out + (size_t)n * 64 + lane * 8;
    *reinterpret_cast<float4*>(po)     = make_float4(o[0], o[1], o[2], o[3]);
    *reinterpret_cast<float4*>(po + 4) = make_float4(o[4], o[5], o[6], o[7]);
}

// ---------------- fused double GEMM ----------------
// Stage 1: h = relu([mean|xb][32,256] @ Wc1 + b1) -> LDS [32][136] bf16 (padded).
// Stage 2: q = h @ Wc2 (+b2 on cols 64..127) -> LDS -> coalesced store.
// A frag stage-1: t<4 from mean[row][t*32+ak..], t>=4 from xb[row][(t-4)*32+ak..].
__global__ __launch_bounds__(256)
void fused_gemm_kernel(const ushort* __restrict__ mean, const ushort* __restrict__ xb,
                       const ushort* __restrict__ Wc1, const float* __restrict__ b1,
                       const ushort* __restrict__ Wc2, const float* __restrict__ b2,
                       ushort* __restrict__ q, int N)
{
    __shared__ ushort hbuf[4][32][136];   // 34 KB
    const int wid = threadIdx.x >> 6;
    const int l = threadIdx.x & 63;
    const int row0 = blockIdx.x * 128 + wid * 32;
    const int ar = l & 15;
    const int ak = (l >> 4) * 8;

    f32x4 zz = {0.f, 0.f, 0.f, 0.f};
    f32x4 acc[2][8];
    #pragma unroll
    for (int g = 0; g < 8; ++g) { acc[0][g] = zz; acc[1][g] = zz; }

    // ---- stage 1: K=256 (mean cols 0..127, xb cols 128..255) ----
    {
        const int rA0 = row0 + ar;
        const int rA1 = row0 + 16 + ar;
        const bool v0 = rA0 < N, v1 = rA1 < N;
        const ushort* m0p = mean + (size_t)rA0 * 128 + ak;
        const ushort* m1p = mean + (size_t)rA1 * 128 + ak;
        const ushort* x0p = xb + (size_t)rA0 * 128 + ak;
        const ushort* x1p = xb + (size_t)rA1 * 128 + ak;
        const short8v* wbase = reinterpret_cast<const short8v*>(Wc1);
        short8v az = {0, 0, 0, 0, 0, 0, 0, 0};
        #pragma unroll
        for (int t = 0; t < 8; ++t) {
            const ushort* p0 = (t < 4) ? (m0p + t * 32) : (x0p + (t - 4) * 32);
            const ushort* p1 = (t < 4) ? (m1p + t * 32) : (x1p + (t - 4) * 32);
            short8v af0 = az, af1 = az;
            if (v0) af0 = *reinterpret_cast<const short8v*>(p0);
            if (v1) af1 = *reinterpret_cast<const short8v*>(p1);
            const short8v* wf = wbase + (size_t)(t * 8) * 64 + l;
            #pragma unroll
            for (int g = 0; g < 8; ++g) {
                short8v bf = wf[g * 64];
                acc[0][g] = __builtin_amdgcn_mfma_f32_16x16x32_bf16(af0, bf, acc[0][g], 0, 0, 0);
                acc[1][g] = __builtin_amdgcn_mfma_f32_16x16x32_bf16(af1, bf, acc[1][g], 0, 0, 0);
            }
        }
    }

    // ---- epilogue 1: bias + relu -> bf16 -> hbuf ----
    {
        const int cr4 = (l >> 4) * 4;
        const int cc = l & 15;
        #pragma unroll
        for (int g = 0; g < 8; ++g) {
            int col = g * 16 + cc;
            float bv = b1[col];
            #pragma unroll
            for (int j = 0; j < 4; ++j) {
                hbuf[wid][cr4 + j][col]      = f2b(fmaxf(acc[0][g][j] + bv, 0.f));
                hbuf[wid][16 + cr4 + j][col] = f2b(fmaxf(acc[1][g][j] + bv, 0.f));
            }
        }
    }
    // same-wave LDS RAW: DS pipe in-order per wave; compiler inserts lgkmcnt.

    // ---- stage 2: K=128 from LDS ----
    #pragma unroll
    for (int g = 0; g < 8; ++g) { acc[0][g] = zz; acc[1][g] = zz; }
    {
        const short8v* wbase = reinterpret_cast<const short8v*>(Wc2);
        #pragma unroll
        for (int t = 0; t < 4; ++t) {
            short8v af0 = *reinterpret_cast<const short8v*>(&hbuf[wid][ar][t * 32 + ak]);
            short8v af1 = *reinterpret_cast<const short8v*>(&hbuf[wid][16 + ar][t * 32 + ak]);
            const short8v* wf = wbase + (size_t)(t * 8) * 64 + l;
            #pragma unroll
            for (int g = 0; g < 8; ++g) {
                short8v bf = wf[g * 64];
                acc[0][g] = __builtin_amdgcn_mfma_f32_16x16x32_bf16(af0, bf, acc[0][g], 0, 0, 0);
                acc[1][g] = __builtin_amdgcn_mfma_f32_16x16x32_bf16(af1, bf, acc[1][g], 0, 0, 0);
            }
        }
    }

    // ---- epilogue 2: +b2 on cols>=64 -> bf16 -> hbuf (overwrite) ----
    {
        const int cr4 = (l >> 4) * 4;
        const int cc = l & 15;
        #pragma unroll
        for (int g = 0; g < 8; ++g) {
            int col = g * 16 + cc;
            float bv = (col >= 64) ? b2[col - 64] : 0.f;
            #pragma unroll
            for (int j = 0; j < 4; ++j) {
                hbuf[wid][cr4 + j][col]      = f2b(acc[0][g][j] + bv);
                hbuf[wid][16 + cr4 + j][col] = f2b(acc[1][g][j] + bv);
            }
        }
    }

    // ---- coalesced store ----
    #pragma unroll
    for (int p = 0; p < 8; ++p) {
        int idx = p * 64 + l;
        int fr = idx >> 4;
        int c8 = idx & 15;
        int r = row0 + fr;
        if (r < N)
            *reinterpret_cast<short8v*>(q + (size_t)r * 128 + c8 * 8) =
                *reinterpret_cast<const short8v*>(&hbuf[wid][fr][c8 * 8]);
    }
}

// ---------------- launch ----------------

extern "C" void kernel_launch(void* const* d_in, const int* in_sizes, int n_in,
                              void* d_out, int out_size, void* d_ws, size_t ws_size,
                              hipStream_t stream)
{
    const float* x   = (const float*)d_in[0];
    const int*   ei  = (const int*)d_in[1];
    const float* W1l = (const float*)d_in[2];
    const float* b1  = (const float*)d_in[3];
    const float* W1r = (const float*)d_in[4];
    const float* W2l = (const float*)d_in[5];
    const float* b2  = (const float*)d_in[6];
    const float* W2r = (const float*)d_in[7];
    float* out = (float*)d_out;

    const int N = NNODES, E = NEDGES;
    const int* src = ei;
    const int* dst = ei + E;

    char* ws = (char*)d_ws;
    int* count  = (int*)ws;                 // N
    int* cursor = count + N;                // N
    int* rp     = cursor + N;               // N+1
    int* bsum   = rp + N + 1;               // 512
    int* esrc   = bsum + 512;               // E
    const size_t MB = 1024u * 1024u;
    ushort* Wc1  = (ushort*)(ws + 4 * MB);                  // 64 KB
    ushort* Wc2  = (ushort*)(ws + 4 * MB + 64 * 1024);      // 32 KB
    ushort* mean = (ushort*)(ws + 4 * MB + 128 * 1024);     // N*128*2 = 25.6 MB
    ushort* xb   = mean + (size_t)N * 128;                  // 25.6 MB
    ushort* q    = xb + (size_t)N * 128;                    // 25.6 MB

    const int nb = (N + 255) / 256;

    hipMemsetAsync(ws, 0, (size_t)2 * N * 4, stream);   // count + cursor

    cast_x_kernel<<<(N * 8 + 255) / 256, 256, 0, stream>>>(x, xb, N);
    hist_wcast_kernel<<<(E + 255) / 256, 256, 0, stream>>>(
        dst, count, W1l, W1r, Wc1, W2l, W2r, Wc2, E);

    block_sum_kernel<<<nb, 256, 0, stream>>>(count, bsum, N);
    scan_bsum_kernel<<<1, 512, 0, stream>>>(bsum, nb);
    scan_write_kernel<<<nb, 256, 0, stream>>>(count, bsum, rp, N, E);
    bucket_kernel<<<(E + 255) / 256, 256, 0, stream>>>(src, dst, rp, cursor, esrc, E);

    gather_mean_bf16<<<(N * 16 + 255) / 256, 256, 0, stream>>>(xb, rp, esrc, mean, N);
    fused_gemm_kernel<<<(N + 127) / 128, 256, 0, stream>>>(mean, xb, Wc1, b1, Wc2, b2, q, N);
    gather_out64_bf16<<<(N * 8 + 255) / 256, 256, 0, stream>>>(q, rp, esrc, out, N);
}

// Round 10
// 248.532 us; speedup vs baseline: 10.1933x; 1.0538x over previous
//
#include <hip/hip_runtime.h>
#include <hip/hip_bf16.h>

// GraphSAGE 2-layer, N=100000, E=640000, d=128 -> 128 -> 64.
// Round 10: fused_gemm was latency-bound (41us, MfmaUtil 8%, VGPR=76 -> no
// prefetch headroom, serialized B-loads). Fix: __launch_bounds__(256,2) +
// explicit double-buffered B/A fragment prefetch in both stages.
// Everything else identical to round 9.

#define NNODES 100000
#define NEDGES 640000

typedef __attribute__((ext_vector_type(8))) short short8v;
typedef __attribute__((ext_vector_type(4))) float f32x4;
typedef unsigned int uint;
typedef unsigned short ushort;

__device__ __forceinline__ float b2f(ushort u) {
    return __uint_as_float(((uint)u) << 16);
}
__device__ __forceinline__ ushort f2b(float f) {   // RTNE
    uint u = __float_as_uint(f);
    return (ushort)((u + 0x7fffu + ((u >> 16) & 1u)) >> 16);
}

// ---------------- streaming cast: x fp32 -> xb bf16 ----------------

__global__ __launch_bounds__(256)
void cast_x_kernel(const float* __restrict__ x, ushort* __restrict__ xb, int N) {
    int i = blockIdx.x * 256 + threadIdx.x;      // N*8 units, 16 floats each
    if (i >= N * 8) return;
    const float* px = x + (size_t)i * 16;
    float4 v0 = *reinterpret_cast<const float4*>(px);
    float4 v1 = *reinterpret_cast<const float4*>(px + 4);
    float4 v2 = *reinterpret_cast<const float4*>(px + 8);
    float4 v3 = *reinterpret_cast<const float4*>(px + 12);
    ushort o[16];
    o[0]=f2b(v0.x); o[1]=f2b(v0.y); o[2]=f2b(v0.z); o[3]=f2b(v0.w);
    o[4]=f2b(v1.x); o[5]=f2b(v1.y); o[6]=f2b(v1.z); o[7]=f2b(v1.w);
    o[8]=f2b(v2.x); o[9]=f2b(v2.y); o[10]=f2b(v2.z); o[11]=f2b(v2.w);
    o[12]=f2b(v3.x); o[13]=f2b(v3.y); o[14]=f2b(v3.z); o[15]=f2b(v3.w);
    ushort* po = xb + (size_t)i * 16;
    *reinterpret_cast<short8v*>(po)     = *reinterpret_cast<short8v*>(o);
    *reinterpret_cast<short8v*>(po + 8) = *reinterpret_cast<short8v*>(o + 8);
}

// ---------------- hist + fragment-major weight casts ----------------
// frag f = (t*8 + g)*64 + l ; element j = B[t*32 + (l>>4)*8 + j][g*16 + (l&15)]
__global__ __launch_bounds__(256)
void hist_wcast_kernel(const int* __restrict__ dst, int* __restrict__ count,
                       const float* __restrict__ W1l, const float* __restrict__ W1r,
                       ushort* __restrict__ Wc1,
                       const float* __restrict__ W2l, const float* __restrict__ W2r,
                       ushort* __restrict__ Wc2, int E)
{
    int i = blockIdx.x * 256 + threadIdx.x;
    if (i < E) atomicAdd(&count[dst[i]], 1);

    if (i < 256 * 16) {   // W1 fragments
        int u = i;
        int t = u >> 9, g = (u >> 6) & 7, l = u & 63;
        int k0 = t * 32 + ((l >> 4) * 8);
        int c = g * 16 + (l & 15);
        ushort o[8];
        #pragma unroll
        for (int j = 0; j < 8; ++j) {
            int k = k0 + j;
            float v = (k < 128) ? W1l[k * 128 + c] : W1r[(k - 128) * 128 + c];
            o[j] = f2b(v);
        }
        *reinterpret_cast<short8v*>(Wc1 + (size_t)u * 8) = *reinterpret_cast<short8v*>(o);
    } else if (i < 256 * 16 + 128 * 16) {   // W2 fragments
        int u = i - 256 * 16;
        int t = u >> 9, g = (u >> 6) & 7, l = u & 63;
        int k0 = t * 32 + ((l >> 4) * 8);
        int c = g * 16 + (l & 15);
        ushort o[8];
        #pragma unroll
        for (int j = 0; j < 8; ++j) {
            int k = k0 + j;
            float v = (c < 64) ? W2l[k * 64 + c] : W2r[k * 64 + (c - 64)];
            o[j] = f2b(v);
        }
        *reinterpret_cast<short8v*>(Wc2 + (size_t)u * 8) = *reinterpret_cast<short8v*>(o);
    }
}

// ---------------- CSR scan + bucket ----------------

__global__ void block_sum_kernel(const int* __restrict__ count, int* __restrict__ bsum, int N) {
    __shared__ int s[256];
    int t = threadIdx.x;
    int i = blockIdx.x * 256 + t;
    s[t] = (i < N) ? count[i] : 0;
    __syncthreads();
    for (int off = 128; off > 0; off >>= 1) {
        if (t < off) s[t] += s[t + off];
        __syncthreads();
    }
    if (t == 0) bsum[blockIdx.x] = s[0];
}

__global__ void scan_bsum_kernel(int* __restrict__ bsum, int nb) {
    __shared__ int s[512];
    int t = threadIdx.x;
    int orig = (t < nb) ? bsum[t] : 0;
    s[t] = orig;
    __syncthreads();
    for (int off = 1; off < 512; off <<= 1) {
        int v = (t >= off) ? s[t - off] : 0;
        __syncthreads();
        s[t] += v;
        __syncthreads();
    }
    if (t < nb) bsum[t] = s[t] - orig;   // exclusive
}

__global__ void scan_write_kernel(const int* __restrict__ count, const int* __restrict__ bsum,
                                  int* __restrict__ rp, int N, int E) {
    __shared__ int s[256];
    int t = threadIdx.x;
    int i = blockIdx.x * 256 + t;
    int orig = (i < N) ? count[i] : 0;
    s[t] = orig;
    __syncthreads();
    for (int off = 1; off < 256; off <<= 1) {
        int v = (t >= off) ? s[t - off] : 0;
        __syncthreads();
        s[t] += v;
        __syncthreads();
    }
    if (i < N) rp[i] = bsum[blockIdx.x] + s[t] - orig;
    if (i == 0) rp[N] = E;
}

__global__ void bucket_kernel(const int* __restrict__ src, const int* __restrict__ dst,
                              const int* __restrict__ rp, int* __restrict__ cursor,
                              int* __restrict__ esrc, int E) {
    int e = blockIdx.x * blockDim.x + threadIdx.x;
    if (e >= E) return;
    int d = dst[e];
    int pos = atomicAdd(&cursor[d], 1);
    esrc[rp[d] + pos] = src[e];
}

// ---------------- gathers (bf16 in, fp32 acc) ----------------

__global__ __launch_bounds__(256)
void gather_mean_bf16(const ushort* __restrict__ xb, const int* __restrict__ rp,
                      const int* __restrict__ esrc, ushort* __restrict__ mean, int N) {
    int gid = blockIdx.x * 256 + threadIdx.x;
    int n = gid >> 4, lane = gid & 15;
    if (n >= N) return;
    int beg = rp[n], end = rp[n + 1];
    float acc[8] = {0.f, 0.f, 0.f, 0.f, 0.f, 0.f, 0.f, 0.f};
    int j = beg;
    for (; j + 2 <= end; j += 2) {
        int s0 = esrc[j], s1 = esrc[j + 1];
        short8v v0 = *reinterpret_cast<const short8v*>(xb + (size_t)s0 * 128 + lane * 8);
        short8v v1 = *reinterpret_cast<const short8v*>(xb + (size_t)s1 * 128 + lane * 8);
        #pragma unroll
        for (int i = 0; i < 8; ++i) acc[i] += b2f((ushort)v0[i]) + b2f((ushort)v1[i]);
    }
    if (j < end) {
        int s0 = esrc[j];
        short8v v0 = *reinterpret_cast<const short8v*>(xb + (size_t)s0 * 128 + lane * 8);
        #pragma unroll
        for (int i = 0; i < 8; ++i) acc[i] += b2f((ushort)v0[i]);
    }
    float inv = 1.0f / fmaxf((float)(end - beg), 1.0f);
    ushort o[8];
    #pragma unroll
    for (int i = 0; i < 8; ++i) o[i] = f2b(acc[i] * inv);
    *reinterpret_cast<short8v*>(mean + (size_t)n * 128 + lane * 8) = *reinterpret_cast<short8v*>(o);
}

__global__ __launch_bounds__(256)
void gather_out64_bf16(const ushort* __restrict__ q, const int* __restrict__ rp,
                       const int* __restrict__ esrc, float* __restrict__ out, int N) {
    int gid = blockIdx.x * 256 + threadIdx.x;
    int n = gid >> 3, lane = gid & 7;
    if (n >= N) return;
    int beg = rp[n], end = rp[n + 1];
    float acc[8] = {0.f, 0.f, 0.f, 0.f, 0.f, 0.f, 0.f, 0.f};
    int j = beg;
    for (; j + 2 <= end; j += 2) {
        int s0 = esrc[j], s1 = esrc[j + 1];
        short8v v0 = *reinterpret_cast<const short8v*>(q + (size_t)s0 * 128 + lane * 8);
        short8v v1 = *reinterpret_cast<const short8v*>(q + (size_t)s1 * 128 + lane * 8);
        #pragma unroll
        for (int i = 0; i < 8; ++i) acc[i] += b2f((ushort)v0[i]) + b2f((ushort)v1[i]);
    }
    if (j < end) {
        int s0 = esrc[j];
        short8v v0 = *reinterpret_cast<const short8v*>(q + (size_t)s0 * 128 + lane * 8);
        #pragma unroll
        for (int i = 0; i < 8; ++i) acc[i] += b2f((ushort)v0[i]);
    }
    float inv = 1.0f / fmaxf((float)(end - beg), 1.0f);
    short8v sv = *reinterpret_cast<const short8v*>(q + (size_t)n * 128 + 64 + lane * 8);
    float o[8];
    #pragma unroll
    for (int i = 0; i < 8; ++i) o[i] = acc[i] * inv + b2f((ushort)sv[i]);
    float* po = out + (size_t)n * 64 + lane * 8;
    *reinterpret_cast<float4*>(po)     = make_float4(o[0], o[1], o[2], o[3]);
    *reinterpret_cast<float4*>(po + 4) = make_float4(o[4], o[5], o[6], o[7]);
}

// ---------------- fused double GEMM (software-pipelined) ----------------
// Stage 1: h = relu([mean|xb][32,256] @ Wc1 + b1) -> LDS [32][136] bf16.
// Stage 2: q = h @ Wc2 (+b2 on cols 64..127) -> LDS -> coalesced store.
// Double-buffered B/A fragment prefetch; launch_bounds(256,2) for VGPR room.
__global__ __launch_bounds__(256, 2)
void fused_gemm_kernel(const ushort* __restrict__ mean, const ushort* __restrict__ xb,
                       const ushort* __restrict__ Wc1, const float* __restrict__ b1,
                       const ushort* __restrict__ Wc2, const float* __restrict__ b2,
                       ushort* __restrict__ q, int N)
{
    __shared__ ushort hbuf[4][32][136];   // 34 KB
    const int wid = threadIdx.x >> 6;
    const int l = threadIdx.x & 63;
    const int row0 = blockIdx.x * 128 + wid * 32;
    const int ar = l & 15;
    const int ak = (l >> 4) * 8;

    f32x4 zz = {0.f, 0.f, 0.f, 0.f};
    short8v az = {0, 0, 0, 0, 0, 0, 0, 0};
    f32x4 acc0[8], acc1[8];
    #pragma unroll
    for (int g = 0; g < 8; ++g) { acc0[g] = zz; acc1[g] = zz; }

    const int rA0 = row0 + ar;
    const int rA1 = row0 + 16 + ar;
    const bool v0 = rA0 < N, v1 = rA1 < N;
    const ushort* m0p = mean + (size_t)rA0 * 128 + ak;
    const ushort* m1p = mean + (size_t)rA1 * 128 + ak;
    const ushort* x0p = xb + (size_t)rA0 * 128 + ak;
    const ushort* x1p = xb + (size_t)rA1 * 128 + ak;
    const short8v* w1l_ = reinterpret_cast<const short8v*>(Wc1) + l;
    const short8v* w2l_ = reinterpret_cast<const short8v*>(Wc2) + l;

    // ---- stage 1: K=256 (mean: t<4, xb: t>=4), double-buffered ----
    short8v bf[2][8];
    short8v af0[2], af1[2];
    #pragma unroll
    for (int g = 0; g < 8; ++g) bf[0][g] = w1l_[g * 64];
    af0[0] = v0 ? *reinterpret_cast<const short8v*>(m0p) : az;
    af1[0] = v1 ? *reinterpret_cast<const short8v*>(m1p) : az;

    #pragma unroll
    for (int t = 0; t < 8; ++t) {
        const int cur = t & 1, nxt = cur ^ 1;
        if (t < 7) {
            const int tn = t + 1;
            const ushort* p0 = (tn < 4) ? (m0p + tn * 32) : (x0p + (tn - 4) * 32);
            const ushort* p1 = (tn < 4) ? (m1p + tn * 32) : (x1p + (tn - 4) * 32);
            af0[nxt] = v0 ? *reinterpret_cast<const short8v*>(p0) : az;
            af1[nxt] = v1 ? *reinterpret_cast<const short8v*>(p1) : az;
            #pragma unroll
            for (int g = 0; g < 8; ++g) bf[nxt][g] = w1l_[(size_t)(tn * 8 + g) * 64];
        }
        #pragma unroll
        for (int g = 0; g < 8; ++g) {
            acc0[g] = __builtin_amdgcn_mfma_f32_16x16x32_bf16(af0[cur], bf[cur][g], acc0[g], 0, 0, 0);
            acc1[g] = __builtin_amdgcn_mfma_f32_16x16x32_bf16(af1[cur], bf[cur][g], acc1[g], 0, 0, 0);
        }
    }

    // prefetch stage-2 B t=0 early (hides under epilogue-1 VALU + LDS writes)
    short8v bf2[2][8];
    #pragma unroll
    for (int g = 0; g < 8; ++g) bf2[0][g] = w2l_[g * 64];

    // ---- epilogue 1: bias + relu -> bf16 -> hbuf ----
    {
        const int cr4 = (l >> 4) * 4;
        const int cc = l & 15;
        #pragma unroll
        for (int g = 0; g < 8; ++g) {
            int col = g * 16 + cc;
            float bv = b1[col];
            #pragma unroll
            for (int j = 0; j < 4; ++j) {
                hbuf[wid][cr4 + j][col]      = f2b(fmaxf(acc0[g][j] + bv, 0.f));
                hbuf[wid][16 + cr4 + j][col] = f2b(fmaxf(acc1[g][j] + bv, 0.f));
            }
        }
    }
    // same-wave LDS RAW: DS pipe in-order per wave; compiler inserts lgkmcnt.

    // ---- stage 2: K=128 from LDS, B double-buffered ----
    #pragma unroll
    for (int g = 0; g < 8; ++g) { acc0[g] = zz; acc1[g] = zz; }
    {
        short8v a2f0[2], a2f1[2];
        a2f0[0] = *reinterpret_cast<const short8v*>(&hbuf[wid][ar][ak]);
        a2f1[0] = *reinterpret_cast<const short8v*>(&hbuf[wid][16 + ar][ak]);
        #pragma unroll
        for (int t = 0; t < 4; ++t) {
            const int cur = t & 1, nxt = cur ^ 1;
            if (t < 3) {
                const int tn = t + 1;
                a2f0[nxt] = *reinterpret_cast<const short8v*>(&hbuf[wid][ar][tn * 32 + ak]);
                a2f1[nxt] = *reinterpret_cast<const short8v*>(&hbuf[wid][16 + ar][tn * 32 + ak]);
                #pragma unroll
                for (int g = 0; g < 8; ++g) bf2[nxt][g] = w2l_[(size_t)(tn * 8 + g) * 64];
            }
            #pragma unroll
            for (int g = 0; g < 8; ++g) {
                acc0[g] = __builtin_amdgcn_mfma_f32_16x16x32_bf16(a2f0[cur], bf2[cur][g], acc0[g], 0, 0, 0);
                acc1[g] = __builtin_amdgcn_mfma_f32_16x16x32_bf16(a2f1[cur], bf2[cur][g], acc1[g], 0, 0, 0);
            }
        }
    }

    // ---- epilogue 2: +b2 on cols>=64 -> bf16 -> hbuf (overwrite) ----
    {
        const int cr4 = (l >> 4) * 4;
        const int cc = l & 15;
        #pragma unroll
        for (int g = 0; g < 8; ++g) {
            int col = g * 16 + cc;
            float bv = (col >= 64) ? b2[col - 64] : 0.f;
            #pragma unroll
            for (int j = 0; j < 4; ++j) {
                hbuf[wid][cr4 + j][col]      = f2b(acc0[g][j] + bv);
                hbuf[wid][16 + cr4 + j][col] = f2b(acc1[g][j] + bv);
            }
        }
    }

    // ---- coalesced store ----
    #pragma unroll
    for (int p = 0; p < 8; ++p) {
        int idx = p * 64 + l;
        int fr = idx >> 4;
        int c8 = idx & 15;
        int r = row0 + fr;
        if (r < N)
            *reinterpret_cast<short8v*>(q + (size_t)r * 128 + c8 * 8) =
                *reinterpret_cast<const short8v*>(&hbuf[wid][fr][c8 * 8]);
    }
}

// ---------------- launch ----------------

extern "C" void kernel_launch(void* const* d_in, const int* in_sizes, int n_in,
                              void* d_out, int out_size, void* d_ws, size_t ws_size,
                              hipStream_t stream)
{
    const float* x   = (const float*)d_in[0];
    const int*   ei  = (const int*)d_in[1];
    const float* W1l = (const float*)d_in[2];
    const float* b1  = (const float*)d_in[3];
    const float* W1r = (const float*)d_in[4];
    const float* W2l = (const float*)d_in[5];
    const float* b2  = (const float*)d_in[6];
    const float* W2r = (const float*)d_in[7];
    float* out = (float*)d_out;

    const int N = NNODES, E = NEDGES;
    const int* src = ei;
    const int* dst = ei + E;

    char* ws = (char*)d_ws;
    int* count  = (int*)ws;                 // N
    int* cursor = count + N;                // N
    int* rp     = cursor + N;               // N+1
    int* bsum   = rp + N + 1;               // 512
    int* esrc   = bsum + 512;               // E
    const size_t MB = 1024u * 1024u;
    ushort* Wc1  = (ushort*)(ws + 4 * MB);                  // 64 KB
    ushort* Wc2  = (ushort*)(ws + 4 * MB + 64 * 1024);      // 32 KB
    ushort* mean = (ushort*)(ws + 4 * MB + 128 * 1024);     // N*128*2 = 25.6 MB
    ushort* xb   = mean + (size_t)N * 128;                  // 25.6 MB
    ushort* q    = xb + (size_t)N * 128;                    // 25.6 MB

    const int nb = (N + 255) / 256;

    hipMemsetAsync(ws, 0, (size_t)2 * N * 4, stream);   // count + cursor

    cast_x_kernel<<<(N * 8 + 255) / 256, 256, 0, stream>>>(x, xb, N);
    hist_wcast_kernel<<<(E + 255) / 256, 256, 0, stream>>>(
        dst, count, W1l, W1r, Wc1, W2l, W2r, Wc2, E);

    block_sum_kernel<<<nb, 256, 0, stream>>>(count, bsum, N);
    scan_bsum_kernel<<<1, 512, 0, stream>>>(bsum, nb);
    scan_write_kernel<<<nb, 256, 0, stream>>>(count, bsum, rp, N, E);
    bucket_kernel<<<(E + 255) / 256, 256, 0, stream>>>(src, dst, rp, cursor, esrc, E);

    gather_mean_bf16<<<(N * 16 + 255) / 256, 256, 0, stream>>>(xb, rp, esrc, mean, N);
    fused_gemm_kernel<<<(N + 127) / 128, 256, 0, stream>>>(mean, xb, Wc1, b1, Wc2, b2, q, N);
    gather_out64_bf16<<<(N * 8 + 255) / 256, 256, 0, stream>>>(q, rp, esrc, out, N);
}

// Round 14
// 239.054 us; speedup vs baseline: 10.5975x; 1.0396x over previous
//
#include <hip/hip_runtime.h>
#include <hip/hip_bf16.h>

// GraphSAGE 2-layer, N=100000, E=640000, d=128 -> 128 -> 64.
// Round 11 (3rd resubmit; broker timeouts): (a) 4-deep memory-level
// parallelism in both gathers; (b) re-fuse cast_x + hist + wcast into one
// prep kernel (no A1-dup). memset stays separate (must precede hist atomics).

#define NNODES 100000
#define NEDGES 640000

typedef __attribute__((ext_vector_type(8))) short short8v;
typedef __attribute__((ext_vector_type(4))) float f32x4;
typedef unsigned int uint;
typedef unsigned short ushort;

__device__ __forceinline__ float b2f(ushort u) {
    return __uint_as_float(((uint)u) << 16);
}
__device__ __forceinline__ ushort f2b(float f) {   // RTNE
    uint u = __float_as_uint(f);
    return (ushort)((u + 0x7fffu + ((u >> 16) & 1u)) >> 16);
}

// ---------------- prep: cast x->xb (streaming) + hist (atomics) + weight casts ----------------
// frag f = (t*8 + g)*64 + l ; element j = B[t*32 + (l>>4)*8 + j][g*16 + (l&15)]
__global__ __launch_bounds__(256)
void prep_kernel(const float* __restrict__ x, ushort* __restrict__ xb,
                 const int* __restrict__ dst, int* __restrict__ count,
                 const float* __restrict__ W1l, const float* __restrict__ W1r,
                 ushort* __restrict__ Wc1,
                 const float* __restrict__ W2l, const float* __restrict__ W2r,
                 ushort* __restrict__ Wc2, int N, int E)
{
    int i = blockIdx.x * 256 + threadIdx.x;

    if (i < N * 8) {   // cast: 16 floats -> 16 bf16 per thread
        const float* px = x + (size_t)i * 16;
        float4 v0 = *reinterpret_cast<const float4*>(px);
        float4 v1 = *reinterpret_cast<const float4*>(px + 4);
        float4 v2 = *reinterpret_cast<const float4*>(px + 8);
        float4 v3 = *reinterpret_cast<const float4*>(px + 12);
        ushort o[16];
        o[0]=f2b(v0.x); o[1]=f2b(v0.y); o[2]=f2b(v0.z); o[3]=f2b(v0.w);
        o[4]=f2b(v1.x); o[5]=f2b(v1.y); o[6]=f2b(v1.z); o[7]=f2b(v1.w);
        o[8]=f2b(v2.x); o[9]=f2b(v2.y); o[10]=f2b(v2.z); o[11]=f2b(v2.w);
        o[12]=f2b(v3.x); o[13]=f2b(v3.y); o[14]=f2b(v3.z); o[15]=f2b(v3.w);
        ushort* po = xb + (size_t)i * 16;
        *reinterpret_cast<short8v*>(po)     = *reinterpret_cast<short8v*>(o);
        *reinterpret_cast<short8v*>(po + 8) = *reinterpret_cast<short8v*>(o + 8);
    }

    if (i < E) atomicAdd(&count[dst[i]], 1);   // hist

    if (i < 256 * 16) {   // W1 fragments
        int u = i;
        int t = u >> 9, g = (u >> 6) & 7, l = u & 63;
        int k0 = t * 32 + ((l >> 4) * 8);
        int c = g * 16 + (l & 15);
        ushort o[8];
        #pragma unroll
        for (int j = 0; j < 8; ++j) {
            int k = k0 + j;
            float v = (k < 128) ? W1l[k * 128 + c] : W1r[(k - 128) * 128 + c];
            o[j] = f2b(v);
        }
        *reinterpret_cast<short8v*>(Wc1 + (size_t)u * 8) = *reinterpret_cast<short8v*>(o);
    } else if (i < 256 * 16 + 128 * 16) {   // W2 fragments
        int u = i - 256 * 16;
        int t = u >> 9, g = (u >> 6) & 7, l = u & 63;
        int k0 = t * 32 + ((l >> 4) * 8);
        int c = g * 16 + (l & 15);
        ushort o[8];
        #pragma unroll
        for (int j = 0; j < 8; ++j) {
            int k = k0 + j;
            float v = (c < 64) ? W2l[k * 64 + c] : W2r[k * 64 + (c - 64)];
            o[j] = f2b(v);
        }
        *reinterpret_cast<short8v*>(Wc2 + (size_t)u * 8) = *reinterpret_cast<short8v*>(o);
    }
}

// ---------------- CSR scan + bucket ----------------

__global__ void block_sum_kernel(const int* __restrict__ count, int* __restrict__ bsum, int N) {
    __shared__ int s[256];
    int t = threadIdx.x;
    int i = blockIdx.x * 256 + t;
    s[t] = (i < N) ? count[i] : 0;
    __syncthreads();
    for (int off = 128; off > 0; off >>= 1) {
        if (t < off) s[t] += s[t + off];
        __syncthreads();
    }
    if (t == 0) bsum[blockIdx.x] = s[0];
}

__global__ void scan_bsum_kernel(int* __restrict__ bsum, int nb) {
    __shared__ int s[512];
    int t = threadIdx.x;
    int orig = (t < nb) ? bsum[t] : 0;
    s[t] = orig;
    __syncthreads();
    for (int off = 1; off < 512; off <<= 1) {
        int v = (t >= off) ? s[t - off] : 0;
        __syncthreads();
        s[t] += v;
        __syncthreads();
    }
    if (t < nb) bsum[t] = s[t] - orig;   // exclusive
}

__global__ void scan_write_kernel(const int* __restrict__ count, const int* __restrict__ bsum,
                                  int* __restrict__ rp, int N, int E) {
    __shared__ int s[256];
    int t = threadIdx.x;
    int i = blockIdx.x * 256 + t;
    int orig = (i < N) ? count[i] : 0;
    s[t] = orig;
    __syncthreads();
    for (int off = 1; off < 256; off <<= 1) {
        int v = (t >= off) ? s[t - off] : 0;
        __syncthreads();
        s[t] += v;
        __syncthreads();
    }
    if (i < N) rp[i] = bsum[blockIdx.x] + s[t] - orig;
    if (i == 0) rp[N] = E;
}

__global__ void bucket_kernel(const int* __restrict__ src, const int* __restrict__ dst,
                              const int* __restrict__ rp, int* __restrict__ cursor,
                              int* __restrict__ esrc, int E) {
    int e = blockIdx.x * blockDim.x + threadIdx.x;
    if (e >= E) return;
    int d = dst[e];
    int pos = atomicAdd(&cursor[d], 1);
    esrc[rp[d] + pos] = src[e];
}

// ---------------- gathers: 4-deep MLP, bf16 in, fp32 acc ----------------

__global__ __launch_bounds__(256)
void gather_mean_bf16(const ushort* __restrict__ xb, const int* __restrict__ rp,
                      const int* __restrict__ esrc, ushort* __restrict__ mean, int N) {
    int gid = blockIdx.x * 256 + threadIdx.x;
    int n = gid >> 4, lane = gid & 15;
    if (n >= N) return;
    int beg = rp[n], end = rp[n + 1];
    float acc[8] = {0.f, 0.f, 0.f, 0.f, 0.f, 0.f, 0.f, 0.f};
    int j = beg;
    for (; j + 4 <= end; j += 4) {
        int s0 = esrc[j], s1 = esrc[j + 1], s2 = esrc[j + 2], s3 = esrc[j + 3];
        short8v v0 = *reinterpret_cast<const short8v*>(xb + (size_t)s0 * 128 + lane * 8);
        short8v v1 = *reinterpret_cast<const short8v*>(xb + (size_t)s1 * 128 + lane * 8);
        short8v v2 = *reinterpret_cast<const short8v*>(xb + (size_t)s2 * 128 + lane * 8);
        short8v v3 = *reinterpret_cast<const short8v*>(xb + (size_t)s3 * 128 + lane * 8);
        #pragma unroll
        for (int i = 0; i < 8; ++i)
            acc[i] += (b2f((ushort)v0[i]) + b2f((ushort)v1[i]))
                    + (b2f((ushort)v2[i]) + b2f((ushort)v3[i]));
    }
    for (; j < end; ++j) {
        int s0 = esrc[j];
        short8v v0 = *reinterpret_cast<const short8v*>(xb + (size_t)s0 * 128 + lane * 8);
        #pragma unroll
        for (int i = 0; i < 8; ++i) acc[i] += b2f((ushort)v0[i]);
    }
    float inv = 1.0f / fmaxf((float)(end - beg), 1.0f);
    ushort o[8];
    #pragma unroll
    for (int i = 0; i < 8; ++i) o[i] = f2b(acc[i] * inv);
    *reinterpret_cast<short8v*>(mean + (size_t)n * 128 + lane * 8) = *reinterpret_cast<short8v*>(o);
}

__global__ __launch_bounds__(256)
void gather_out64_bf16(const ushort* __restrict__ q, const int* __restrict__ rp,
                       const int* __restrict__ esrc, float* __restrict__ out, int N) {
    int gid = blockIdx.x * 256 + threadIdx.x;
    int n = gid >> 3, lane = gid & 7;
    if (n >= N) return;
    int beg = rp[n], end = rp[n + 1];
    float acc[8] = {0.f, 0.f, 0.f, 0.f, 0.f, 0.f, 0.f, 0.f};
    int j = beg;
    for (; j + 4 <= end; j += 4) {
        int s0 = esrc[j], s1 = esrc[j + 1], s2 = esrc[j + 2], s3 = esrc[j + 3];
        short8v v0 = *reinterpret_cast<const short8v*>(q + (size_t)s0 * 128 + lane * 8);
        short8v v1 = *reinterpret_cast<const short8v*>(q + (size_t)s1 * 128 + lane * 8);
        short8v v2 = *reinterpret_cast<const short8v*>(q + (size_t)s2 * 128 + lane * 8);
        short8v v3 = *reinterpret_cast<const short8v*>(q + (size_t)s3 * 128 + lane * 8);
        #pragma unroll
        for (int i = 0; i < 8; ++i)
            acc[i] += (b2f((ushort)v0[i]) + b2f((ushort)v1[i]))
                    + (b2f((ushort)v2[i]) + b2f((ushort)v3[i]));
    }
    for (; j < end; ++j) {
        int s0 = esrc[j];
        short8v v0 = *reinterpret_cast<const short8v*>(q + (size_t)s0 * 128 + lane * 8);
        #pragma unroll
        for (int i = 0; i < 8; ++i) acc[i] += b2f((ushort)v0[i]);
    }
    float inv = 1.0f / fmaxf((float)(end - beg), 1.0f);
    short8v sv = *reinterpret_cast<const short8v*>(q + (size_t)n * 128 + 64 + lane * 8);
    float o[8];
    #pragma unroll
    for (int i = 0; i < 8; ++i) o[i] = acc[i] * inv + b2f((ushort)sv[i]);
    float* po = out + (size_t)n * 64 + lane * 8;
    *reinterpret_cast<float4*>(po)     = make_float4(o[0], o[1], o[2], o[3]);
    *reinterpret_cast<float4*>(po + 4) = make_float4(o[4], o[5], o[6], o[7]);
}

// ---------------- fused double GEMM (software-pipelined, from round 10) ----------------
__global__ __launch_bounds__(256, 2)
void fused_gemm_kernel(const ushort* __restrict__ mean, const ushort* __restrict__ xb,
                       const ushort* __restrict__ Wc1, const float* __restrict__ b1,
                       const ushort* __restrict__ Wc2, const float* __restrict__ b2,
                       ushort* __restrict__ q, int N)
{
    __shared__ ushort hbuf[4][32][136];   // 34 KB
    const int wid = threadIdx.x >> 6;
    const int l = threadIdx.x & 63;
    const int row0 = blockIdx.x * 128 + wid * 32;
    const int ar = l & 15;
    const int ak = (l >> 4) * 8;

    f32x4 zz = {0.f, 0.f, 0.f, 0.f};
    short8v az = {0, 0, 0, 0, 0, 0, 0, 0};
    f32x4 acc0[8], acc1[8];
    #pragma unroll
    for (int g = 0; g < 8; ++g) { acc0[g] = zz; acc1[g] = zz; }

    const int rA0 = row0 + ar;
    const int rA1 = row0 + 16 + ar;
    const bool v0 = rA0 < N, v1 = rA1 < N;
    const ushort* m0p = mean + (size_t)rA0 * 128 + ak;
    const ushort* m1p = mean + (size_t)rA1 * 128 + ak;
    const ushort* x0p = xb + (size_t)rA0 * 128 + ak;
    const ushort* x1p = xb + (size_t)rA1 * 128 + ak;
    const short8v* w1l_ = reinterpret_cast<const short8v*>(Wc1) + l;
    const short8v* w2l_ = reinterpret_cast<const short8v*>(Wc2) + l;

    // ---- stage 1: K=256 (mean: t<4, xb: t>=4), double-buffered ----
    short8v bf[2][8];
    short8v af0[2], af1[2];
    #pragma unroll
    for (int g = 0; g < 8; ++g) bf[0][g] = w1l_[g * 64];
    af0[0] = v0 ? *reinterpret_cast<const short8v*>(m0p) : az;
    af1[0] = v1 ? *reinterpret_cast<const short8v*>(m1p) : az;

    #pragma unroll
    for (int t = 0; t < 8; ++t) {
        const int cur = t & 1, nxt = cur ^ 1;
        if (t < 7) {
            const int tn = t + 1;
            const ushort* p0 = (tn < 4) ? (m0p + tn * 32) : (x0p + (tn - 4) * 32);
            const ushort* p1 = (tn < 4) ? (m1p + tn * 32) : (x1p + (tn - 4) * 32);
            af0[nxt] = v0 ? *reinterpret_cast<const short8v*>(p0) : az;
            af1[nxt] = v1 ? *reinterpret_cast<const short8v*>(p1) : az;
            #pragma unroll
            for (int g = 0; g < 8; ++g) bf[nxt][g] = w1l_[(size_t)(tn * 8 + g) * 64];
        }
        #pragma unroll
        for (int g = 0; g < 8; ++g) {
            acc0[g] = __builtin_amdgcn_mfma_f32_16x16x32_bf16(af0[cur], bf[cur][g], acc0[g], 0, 0, 0);
            acc1[g] = __builtin_amdgcn_mfma_f32_16x16x32_bf16(af1[cur], bf[cur][g], acc1[g], 0, 0, 0);
        }
    }

    // prefetch stage-2 B t=0 early
    short8v bf2[2][8];
    #pragma unroll
    for (int g = 0; g < 8; ++g) bf2[0][g] = w2l_[g * 64];

    // ---- epilogue 1 ----
    {
        const int cr4 = (l >> 4) * 4;
        const int cc = l & 15;
        #pragma unroll
        for (int g = 0; g < 8; ++g) {
            int col = g * 16 + cc;
            float bv = b1[col];
            #pragma unroll
            for (int j = 0; j < 4; ++j) {
                hbuf[wid][cr4 + j][col]      = f2b(fmaxf(acc0[g][j] + bv, 0.f));
                hbuf[wid][16 + cr4 + j][col] = f2b(fmaxf(acc1[g][j] + bv, 0.f));
            }
        }
    }

    // ---- stage 2: K=128 from LDS ----
    #pragma unroll
    for (int g = 0; g < 8; ++g) { acc0[g] = zz; acc1[g] = zz; }
    {
        short8v a2f0[2], a2f1[2];
        a2f0[0] = *reinterpret_cast<const short8v*>(&hbuf[wid][ar][ak]);
        a2f1[0] = *reinterpret_cast<const short8v*>(&hbuf[wid][16 + ar][ak]);
        #pragma unroll
        for (int t = 0; t < 4; ++t) {
            const int cur = t & 1, nxt = cur ^ 1;
            if (t < 3) {
                const int tn = t + 1;
                a2f0[nxt] = *reinterpret_cast<const short8v*>(&hbuf[wid][ar][tn * 32 + ak]);
                a2f1[nxt] = *reinterpret_cast<const short8v*>(&hbuf[wid][16 + ar][tn * 32 + ak]);
                #pragma unroll
                for (int g = 0; g < 8; ++g) bf2[nxt][g] = w2l_[(size_t)(tn * 8 + g) * 64];
            }
            #pragma unroll
            for (int g = 0; g < 8; ++g) {
                acc0[g] = __builtin_amdgcn_mfma_f32_16x16x32_bf16(a2f0[cur], bf2[cur][g], acc0[g], 0, 0, 0);
                acc1[g] = __builtin_amdgcn_mfma_f32_16x16x32_bf16(a2f1[cur], bf2[cur][g], acc1[g], 0, 0, 0);
            }
        }
    }

    // ---- epilogue 2 ----
    {
        const int cr4 = (l >> 4) * 4;
        const int cc = l & 15;
        #pragma unroll
        for (int g = 0; g < 8; ++g) {
            int col = g * 16 + cc;
            float bv = (col >= 64) ? b2[col - 64] : 0.f;
            #pragma unroll
            for (int j = 0; j < 4; ++j) {
                hbuf[wid][cr4 + j][col]      = f2b(acc0[g][j] + bv);
                hbuf[wid][16 + cr4 + j][col] = f2b(acc1[g][j] + bv);
            }
        }
    }

    // ---- coalesced store ----
    #pragma unroll
    for (int p = 0; p < 8; ++p) {
        int idx = p * 64 + l;
        int fr = idx >> 4;
        int c8 = idx & 15;
        int r = row0 + fr;
        if (r < N)
            *reinterpret_cast<short8v*>(q + (size_t)r * 128 + c8 * 8) =
                *reinterpret_cast<const short8v*>(&hbuf[wid][fr][c8 * 8]);
    }
}

// ---------------- launch ----------------

extern "C" void kernel_launch(void* const* d_in, const int* in_sizes, int n_in,
                              void* d_out, int out_size, void* d_ws, size_t ws_size,
                              hipStream_t stream)
{
    const float* x   = (const float*)d_in[0];
    const int*   ei  = (const int*)d_in[1];
    const float* W1l = (const float*)d_in[2];
    const float* b1  = (const float*)d_in[3];
    const float* W1r = (const float*)d_in[4];
    const float* W2l = (const float*)d_in[5];
    const float* b2  = (const float*)d_in[6];
    const float* W2r = (const float*)d_in[7];
    float* out = (float*)d_out;

    const int N = NNODES, E = NEDGES;
    const int* src = ei;
    const int* dst = ei + E;

    char* ws = (char*)d_ws;
    int* count  = (int*)ws;                 // N
    int* cursor = count + N;                // N
    int* rp     = cursor + N;               // N+1
    int* bsum   = rp + N + 1;               // 512
    int* esrc   = bsum + 512;               // E
    const size_t MB = 1024u * 1024u;
    ushort* Wc1  = (ushort*)(ws + 4 * MB);                  // 64 KB
    ushort* Wc2  = (ushort*)(ws + 4 * MB + 64 * 1024);      // 32 KB
    ushort* mean = (ushort*)(ws + 4 * MB + 128 * 1024);     // 25.6 MB
    ushort* xb   = mean + (size_t)N * 128;                  // 25.6 MB
    ushort* q    = xb + (size_t)N * 128;                    // 25.6 MB

    const int nb = (N + 255) / 256;

    hipMemsetAsync(ws, 0, (size_t)2 * N * 4, stream);   // count + cursor (must precede hist)

    prep_kernel<<<(N * 8 + 255) / 256, 256, 0, stream>>>(
        x, xb, dst, count, W1l, W1r, Wc1, W2l, W2r, Wc2, N, E);

    block_sum_kernel<<<nb, 256, 0, stream>>>(count, bsum, N);
    scan_bsum_kernel<<<1, 512, 0, stream>>>(bsum, nb);
    scan_write_kernel<<<nb, 256, 0, stream>>>(count, bsum, rp, N, E);
    bucket_kernel<<<(E + 255) / 256, 256, 0, stream>>>(src, dst, rp, cursor, esrc, E);

    gather_mean_bf16<<<(N * 16 + 255) / 256, 256, 0, stream>>>(xb, rp, esrc, mean, N);
    fused_gemm_kernel<<<(N + 127) / 128, 256, 0, stream>>>(mean, xb, Wc1, b1, Wc2, b2, q, N);
    gather_out64_bf16<<<(N * 8 + 255) / 256, 256, 0, stream>>>(q, rp, esrc, out, N);
}